// Round 10
// baseline (479.222 us; speedup 1.0000x reference)
//
#include <hip/hip_runtime.h>
#include <stdint.h>

#define EMB 128
#define LAYERS 3
#define NGRAPHS 64
#define BN_EPS 1e-5f

// CSR bucket build parameters. NOTE: packing requires N < 65536 (N=50000 here)
// and E < 2^32. Bucket = 64 consecutive dst nodes; 8 XCD-sliced sublists of
// capacity 256 each (mean occupancy 128, 11 sigma headroom); overflow spills
// to a global list (correct but slow path; statistically never taken).
#define BSH 6
#define BNODES 64
#define SUBCAP 256
#define BCAP (8 * SUBCAP + 256)
#define OVFCAP 8192

typedef short short8 __attribute__((ext_vector_type(8)));
typedef float float4v __attribute__((ext_vector_type(4)));
typedef unsigned short ushort4v __attribute__((ext_vector_type(4)));

__device__ __forceinline__ unsigned short f2bf(float f) {
    union { float f; unsigned int i; } v; v.f = f;
    unsigned int x = v.i;
    unsigned int r = x + 0x7FFFu + ((x >> 16) & 1u);
    return (unsigned short)(r >> 16);
}
__device__ __forceinline__ float bflo(unsigned int u) {
    union { unsigned int i; float f; } v; v.i = u << 16; return v.f;
}
__device__ __forceinline__ float bfhi(unsigned int u) {
    union { unsigned int i; float f; } v; v.i = u & 0xffff0000u; return v.f;
}
__device__ __forceinline__ unsigned int packbf(float a, float b) {
    return (unsigned int)f2bf(a) | ((unsigned int)f2bf(b) << 16);
}

// f32 -> bf16 (RNE), three concatenated segments in one dispatch
__global__ __launch_bounds__(256) void conv_bf16_3(
    const float* __restrict__ a, unsigned short* __restrict__ oa, int na,
    const float* __restrict__ b, unsigned short* __restrict__ ob, int nb,
    const float* __restrict__ c, unsigned short* __restrict__ oc, int nc)
{
    int i = blockIdx.x * 256 + threadIdx.x;
    int stride = gridDim.x * 256;
    for (int t = i; t < na + nb + nc; t += stride) {
        if (t < na) oa[t] = f2bf(a[t]);
        else if (t < na + nb) ob[t - na] = f2bf(b[t - na]);
        else oc[t - na - nb] = f2bf(c[t - na - nb]);
    }
}

// ---------------------------------------------------------------------------
// GEMM (input embedding only): C = A[M,K] @ B[Ntot,K]^T + bias
// ---------------------------------------------------------------------------
template<int K, bool A_IS_BF16, bool RELU, bool OUT_BF16>
__global__ __launch_bounds__(256) void gemm_bt(
    const void* __restrict__ Av, const unsigned short* __restrict__ B,
    const float* __restrict__ bias, void* __restrict__ Cv,
    int M, int Ntot)
{
    const int wave = threadIdx.x >> 6;
    const int lane = threadIdx.x & 63;
    const int q    = lane >> 4;
    const int ln   = lane & 15;
    const int m_base = blockIdx.x * 64 + wave * 16;
    const int n_base = blockIdx.y * 64;

    float4v acc[4];
#pragma unroll
    for (int i = 0; i < 4; ++i) acc[i] = (float4v){0.f, 0.f, 0.f, 0.f};

    int mrow = m_base + ln;
    if (mrow >= M) mrow = M - 1;

    const int KSTEPS = K / 32;
#pragma unroll
    for (int ks = 0; ks < KSTEPS; ++ks) {
        const int k0 = ks * 32 + q * 8;
        short8 afrag;
        if constexpr (A_IS_BF16) {
            const unsigned short* A = (const unsigned short*)Av;
            afrag = *reinterpret_cast<const short8*>(A + (size_t)mrow * K + k0);
        } else {
            const float* A = (const float*)Av;
            const float4v* p = reinterpret_cast<const float4v*>(A + (size_t)mrow * K + k0);
            float4v f0 = p[0], f1 = p[1];
            afrag[0] = (short)f2bf(f0[0]); afrag[1] = (short)f2bf(f0[1]);
            afrag[2] = (short)f2bf(f0[2]); afrag[3] = (short)f2bf(f0[3]);
            afrag[4] = (short)f2bf(f1[0]); afrag[5] = (short)f2bf(f1[1]);
            afrag[6] = (short)f2bf(f1[2]); afrag[7] = (short)f2bf(f1[3]);
        }
#pragma unroll
        for (int nt = 0; nt < 4; ++nt) {
            const short8 bfrag = *reinterpret_cast<const short8*>(
                B + (size_t)(n_base + nt * 16 + ln) * K + k0);
            acc[nt] = __builtin_amdgcn_mfma_f32_16x16x32_bf16(afrag, bfrag, acc[nt], 0, 0, 0);
        }
    }

#pragma unroll
    for (int nt = 0; nt < 4; ++nt) {
        const int n = n_base + nt * 16 + ln;
        const float bv = bias[n];
#pragma unroll
        for (int r = 0; r < 4; ++r) {
            const int m = m_base + q * 4 + r;
            if (m < M) {
                float v = acc[nt][r] + bv;
                if constexpr (RELU) v = v > 0.f ? v : 0.f;
                if constexpr (OUT_BF16)
                    ((unsigned short*)Cv)[(size_t)m * Ntot + n] = f2bf(v);
                else
                    ((float*)Cv)[(size_t)m * Ntot + n] = v;
            }
        }
    }
}

// ---------------------------------------------------------------------------
// Fused MLP v5: weights register-resident, 32-node tiles, next-tile register
// prefetch (ag load for tile t+1 issued before stage-1 of tile t).
// ---------------------------------------------------------------------------
__global__ __launch_bounds__(512) void fused_mlp(
    const unsigned short* __restrict__ ag, const unsigned short* __restrict__ W1,
    const float* __restrict__ b1, const unsigned short* __restrict__ W2,
    const float* __restrict__ b2, float* __restrict__ h2,
    float* __restrict__ sums2, int M, int ntiles)
{
    __shared__ unsigned short ag_lds[32 * 136];
    __shared__ unsigned short Ylds[32 * 264];
    const int tid = threadIdx.x;
    const int wave = tid >> 6, lane = tid & 63;
    const int q = lane >> 4, ln = lane & 15;
    const int k0 = q * 8;
    float* slice = sums2 + (size_t)(blockIdx.x & 31) * 256;

    // --- load resident weight fragments (once per block) ---
    short8 w1f[2][4], w2f[8];
#pragma unroll
    for (int c = 0; c < 2; ++c) {
        const int ct = wave * 2 + c;
#pragma unroll
        for (int ks = 0; ks < 4; ++ks)
            w1f[c][ks] = *reinterpret_cast<const short8*>(
                W1 + (size_t)(ct * 16 + ln) * 128 + ks * 32 + k0);
    }
#pragma unroll
    for (int ks = 0; ks < 8; ++ks)
        w2f[ks] = *reinterpret_cast<const short8*>(
            W2 + (size_t)(wave * 16 + ln) * 256 + ks * 32 + k0);
    float4v b1v[2];
    b1v[0] = *reinterpret_cast<const float4v*>(b1 + (wave * 2) * 16 + q * 4);
    b1v[1] = *reinterpret_cast<const float4v*>(b1 + (wave * 2 + 1) * 16 + q * 4);
    const float4v b2v = *reinterpret_cast<const float4v*>(b2 + wave * 16 + q * 4);

    // staging slot for this thread: node nd, 8 channels at ch
    const int nd = tid >> 4, ch = (tid & 15) * 8;
    uint4 stage;
    {
        int ng = blockIdx.x * 32 + nd; if (ng >= M) ng = M - 1;
        stage = *reinterpret_cast<const uint4*>(ag + (size_t)ng * 128 + ch);
    }

    for (int t = blockIdx.x; t < ntiles; t += gridDim.x) {
        const int nbase = t * 32;
        __syncthreads();   // previous iteration's LDS readers done
        *reinterpret_cast<uint4*>(&ag_lds[nd * 136 + ch]) = stage;
        __syncthreads();

        // prefetch next tile while stage-1/2 compute
        const int tn = t + gridDim.x;
        if (tn < ntiles) {
            int ng = tn * 32 + nd; if (ng >= M) ng = M - 1;
            stage = *reinterpret_cast<const uint4*>(ag + (size_t)ng * 128 + ch);
        }

        // stage 1: Y^T tile (channels x nodes), per 16-node sub-tile nt
#pragma unroll
        for (int nt = 0; nt < 2; ++nt) {
            short8 agf[4];
#pragma unroll
            for (int ks = 0; ks < 4; ++ks)
                agf[ks] = *reinterpret_cast<const short8*>(
                    &ag_lds[(nt * 16 + ln) * 136 + ks * 32 + k0]);
#pragma unroll
            for (int c = 0; c < 2; ++c) {
                float4v acc = (float4v){0.f, 0.f, 0.f, 0.f};
#pragma unroll
                for (int ks = 0; ks < 4; ++ks)
                    acc = __builtin_amdgcn_mfma_f32_16x16x32_bf16(
                        w1f[c][ks], agf[ks], acc, 0, 0, 0);
                const int c0 = (wave * 2 + c) * 16 + q * 4;
                ushort4v pk;
                pk[0] = f2bf(fmaxf(acc[0] + b1v[c][0], 0.f));
                pk[1] = f2bf(fmaxf(acc[1] + b1v[c][1], 0.f));
                pk[2] = f2bf(fmaxf(acc[2] + b1v[c][2], 0.f));
                pk[3] = f2bf(fmaxf(acc[3] + b1v[c][3], 0.f));
                *reinterpret_cast<ushort4v*>(&Ylds[(nt * 16 + ln) * 264 + c0]) = pk;
            }
        }
        __syncthreads();

        // stage 2: h2 tile + BN partial stats (accumulated over both nt)
        float s[4], s2[4];
#pragma unroll
        for (int r = 0; r < 4; ++r) { s[r] = 0.f; s2[r] = 0.f; }
        const int c0 = wave * 16 + q * 4;
#pragma unroll
        for (int nt = 0; nt < 2; ++nt) {
            short8 yf[8];
#pragma unroll
            for (int ks = 0; ks < 8; ++ks)
                yf[ks] = *reinterpret_cast<const short8*>(
                    &Ylds[(nt * 16 + ln) * 264 + ks * 32 + k0]);
            float4v acc = (float4v){0.f, 0.f, 0.f, 0.f};
#pragma unroll
            for (int ks = 0; ks < 8; ++ks)
                acc = __builtin_amdgcn_mfma_f32_16x16x32_bf16(
                    w2f[ks], yf[ks], acc, 0, 0, 0);
            const int node = nbase + nt * 16 + ln;
            const bool valid = (node < M);
            float4v v;
            v[0] = acc[0] + b2v[0]; v[1] = acc[1] + b2v[1];
            v[2] = acc[2] + b2v[2]; v[3] = acc[3] + b2v[3];
            if (valid)
                *reinterpret_cast<float4v*>(h2 + (size_t)node * 128 + c0) = v;
#pragma unroll
            for (int r = 0; r < 4; ++r) {
                const float x = valid ? v[r] : 0.f;
                s[r] += x; s2[r] += x * x;
            }
        }
#pragma unroll
        for (int off = 1; off < 16; off <<= 1) {
#pragma unroll
            for (int r = 0; r < 4; ++r) {
                s[r]  += __shfl_xor(s[r],  off);
                s2[r] += __shfl_xor(s2[r], off);
            }
        }
        if (ln == 0) {
#pragma unroll
            for (int r = 0; r < 4; ++r) {
                atomicAdd(&slice[c0 + r], s[r]);
                atomicAdd(&slice[128 + c0 + r], s2[r]);
            }
        }
    }
}

// ---------------------------------------------------------------------------
// Fold 32 striped stat slices into per-channel BN (scale, shift)
// ---------------------------------------------------------------------------
__global__ __launch_bounds__(128) void bn_coef(
    const float* __restrict__ sums2, const float* __restrict__ gamma,
    const float* __restrict__ beta, float* __restrict__ coef, float invN)
{
    const int c = threadIdx.x;
    float s = 0.f, ss = 0.f;
    for (int k = 0; k < 32; ++k) {
        s  += sums2[k * 256 + c];
        ss += sums2[k * 256 + 128 + c];
    }
    float mu = s * invN;
    float var = ss * invN - mu * mu;
    float sc = gamma[c] * rsqrtf(fmaxf(var, 0.f) + BN_EPS);
    coef[c] = sc;
    coef[128 + c] = beta[c] - mu * sc;
}

// ---------------------------------------------------------------------------
// CSR build v2: bucketed, write-coalesced, replaces hist+scan+fill.
// ---------------------------------------------------------------------------
__global__ __launch_bounds__(256) void edge_scatter(
    const int* __restrict__ ei, int* __restrict__ subcnt,
    uint2* __restrict__ staging, int* __restrict__ ovfcnt,
    uint4* __restrict__ ovfbuf, int E)
{
    const int sub = blockIdx.x & 7;
    const int e = blockIdx.x * 256 + threadIdx.x;
    if (e >= E) return;
    const unsigned int src = (unsigned int)ei[e];
    const int dst = ei[E + e];
    const int b = dst >> BSH;
    const unsigned int rx = src | ((unsigned int)(dst & (BNODES - 1)) << 16);
    const int sl = b * 8 + sub;
    const int pos = atomicAdd(&subcnt[sl], 1);
    if (pos < SUBCAP) {
        staging[(size_t)sl * SUBCAP + pos] = make_uint2(rx, (unsigned int)e);
    } else {
        int op = atomicAdd(ovfcnt, 1);
        if (op < OVFCAP)
            ovfbuf[op] = make_uint4(rx, (unsigned int)e, (unsigned int)b, 0u);
    }
}

// Exclusive prefix over per-bucket totals (single block).
__global__ __launch_bounds__(256) void bucket_scan(
    const int* __restrict__ subcnt, int* __restrict__ bucketbase, int B)
{
    const int t = threadIdx.x;
    int tot[4]; int mysum = 0;
#pragma unroll
    for (int j = 0; j < 4; ++j) {
        const int b = t * 4 + j;
        int s = 0;
        if (b < B)
            for (int k = 0; k < 8; ++k) s += subcnt[b * 8 + k];
        tot[j] = s; mysum += s;
    }
    const int lane = t & 63, wv = t >> 6;
    int iv = mysum;
#pragma unroll
    for (int off = 1; off < 64; off <<= 1) {
        int u = __shfl_up(iv, off);
        if (lane >= off) iv += u;
    }
    __shared__ int ws[4];
    if (lane == 63) ws[wv] = iv;
    __syncthreads();
    int woff = 0;
    for (int j = 0; j < wv; ++j) woff += ws[j];
    int ex = woff + iv - mysum;
#pragma unroll
    for (int j = 0; j < 4; ++j) {
        const int b = t * 4 + j;
        if (b < B) bucketbase[b] = ex;
        ex += tot[j];
    }
    if (t == 255) bucketbase[B] = ex;
}

// Phase D: one block per bucket. LDS counting-sort -> sequential CSR arrays.
__global__ __launch_bounds__(256) void csr_build(
    const int* __restrict__ subcnt, const int* __restrict__ bucketbase,
    const uint2* __restrict__ staging, const int* __restrict__ ovfcnt,
    const uint4* __restrict__ ovfbuf,
    int* __restrict__ asrc, int* __restrict__ aeid,
    int* __restrict__ rowptr, int N, int E)
{
    __shared__ uint2 recs[BCAP];
    __shared__ int scnt[8], sp[8], cnt[BNODES], rp_s[BNODES], wp2[BNODES];
    __shared__ int totsh;
    const int b = blockIdx.x;
    const int tid = threadIdx.x;
    if (tid < 8) scnt[tid] = min(subcnt[b * 8 + tid], SUBCAP);
    if (tid < BNODES) cnt[tid] = 0;
    __syncthreads();
    if (tid == 0) {
        int a = 0;
        for (int s = 0; s < 8; ++s) { sp[s] = a; a += scnt[s]; }
        totsh = a;
    }
    __syncthreads();
    // load sublists into LDS + per-node counts
    for (int s = 0; s < 8; ++s) {
        const int L = scnt[s];
        const uint2* srcp = staging + (size_t)(b * 8 + s) * SUBCAP;
        for (int i = tid; i < L; i += 256) {
            uint2 r = srcp[i];
            recs[sp[s] + i] = r;
            atomicAdd(&cnt[(r.x >> 16) & (BNODES - 1)], 1);
        }
    }
    __syncthreads();
    // overflow records (statistically never taken; kept for correctness)
    const int ov = min(*ovfcnt, OVFCAP);
    if (ov > 0) {
        for (int i = tid; i < ov; i += 256) {
            uint4 r = ovfbuf[i];
            if ((int)r.z == b) {
                int p = atomicAdd(&totsh, 1);
                if (p < BCAP) {
                    recs[p] = make_uint2(r.x, r.y);
                    atomicAdd(&cnt[(r.x >> 16) & (BNODES - 1)], 1);
                }
            }
        }
    }
    __syncthreads();
    const int total = min(totsh, BCAP);
    // exclusive prefix over 64 per-node counts (wave 0)
    if (tid < BNODES) {
        int v = cnt[tid];
        int iv = v;
#pragma unroll
        for (int off = 1; off < 64; off <<= 1) {
            int u = __shfl_up(iv, off);
            if (tid >= off) iv += u;
        }
        rp_s[tid] = iv - v;
        wp2[tid] = 0;
    }
    __syncthreads();
    const int base = bucketbase[b];
    const int n0 = b * BNODES;
    const int nn = min(BNODES, N - n0);
    if (tid < nn) rowptr[n0 + tid] = base + rp_s[tid];
    if (b == 0 && tid == 0) rowptr[N] = E;
    // scatter within the bucket's contiguous range (L2-coalesced)
    for (int i = tid; i < total; i += 256) {
        uint2 r = recs[i];
        const int d = (r.x >> 16) & (BNODES - 1);
        const int pos = base + rp_s[d] + atomicAdd(&wp2[d], 1);
        asrc[pos] = (int)(r.x & 0xFFFFu);
        aeid[pos] = (int)r.y;
    }
}

// ---------------------------------------------------------------------------
// mom[n][k] = sum of eattr over in-edges (gather, no atomics)
// v2: scalar row bounds, 4-deep gather batches
// ---------------------------------------------------------------------------
__global__ __launch_bounds__(256) void mom_gather(
    const int* __restrict__ aeid, const int* __restrict__ rowptr,
    const float* __restrict__ eattr, float* __restrict__ mom, int N)
{
    const int lane = threadIdx.x & 63;
    const int gwave = (blockIdx.x * 256 + threadIdx.x) >> 6;
    const int nwaves = (gridDim.x * 256) >> 6;
    const int j = lane >> 4, k = lane & 15;
    for (int n = gwave; n < N; n += nwaves) {
        const int s = __builtin_amdgcn_readfirstlane(rowptr[n]);
        const int e = __builtin_amdgcn_readfirstlane(rowptr[n + 1]);
        float acc = 0.f;
        int p = s + j;
        for (; p + 12 < e; p += 16) {
            const int e0 = aeid[p], e1 = aeid[p + 4];
            const int e2 = aeid[p + 8], e3 = aeid[p + 12];
            const float v0 = eattr[(size_t)e0 * 16 + k];
            const float v1 = eattr[(size_t)e1 * 16 + k];
            const float v2 = eattr[(size_t)e2 * 16 + k];
            const float v3 = eattr[(size_t)e3 * 16 + k];
            acc += (v0 + v1) + (v2 + v3);
        }
        for (; p < e; p += 4)
            acc += eattr[(size_t)aeid[p] * 16 + k];
        acc += __shfl_xor(acc, 16);
        acc += __shfl_xor(acc, 32);
        if (lane < 16) mom[(size_t)n * 16 + lane] = acc;
    }
}

// ---------------------------------------------------------------------------
// Gather aggregation over bf16 h:
// ag[n] = bf16( h[n] + Σ_in h[src] + be*(deg+1) + We·mom[n] )
// v9: dual node streams per wave (nodes 2w, 2w+1). While both streams have
// >=8 edges: issue 8+8 independent gathers (doubles memory-level parallelism,
// no cross-lane ops in the address path — r5/r8 lesson). Drain each stream
// with r7's proven 16-group + zero-row-clamped 8-group pattern.
// ---------------------------------------------------------------------------
__global__ __launch_bounds__(256) void aggregate_kernel(
    const unsigned short* __restrict__ h, const int* __restrict__ asrc,
    const int* __restrict__ rowptr, const float* __restrict__ mom,
    const float* __restrict__ We, const float* __restrict__ be,
    unsigned short* __restrict__ ag, int N)
{
    const int lane = threadIdx.x & 63;
    const int gwave = (blockIdx.x * 256 + threadIdx.x) >> 6;
    const int nwaves = (gridDim.x * 256) >> 6;
    const int c0 = 2 * lane;

    float w0[16], w1[16];
#pragma unroll
    for (int k = 0; k < 16; ++k) {
        w0[k] = We[c0 * 16 + k];
        w1[k] = We[(c0 + 1) * 16 + k];
    }
    const float b0 = be[c0], b1 = be[c0 + 1];

    for (int n0 = gwave * 2; n0 < N; n0 += nwaves * 2) {
        const int n1 = n0 + 1;
        const bool has1 = (n1 < N);
        const int s0 = __builtin_amdgcn_readfirstlane(rowptr[n0]);
        const int e0 = __builtin_amdgcn_readfirstlane(rowptr[n0 + 1]);
        int s1 = 0, e1 = 0;
        if (has1) {
            s1 = __builtin_amdgcn_readfirstlane(rowptr[n1]);
            e1 = __builtin_amdgcn_readfirstlane(rowptr[n1 + 1]);
        }

        unsigned int self0 = *reinterpret_cast<const unsigned int*>(
            h + (size_t)n0 * 128 + c0);
        float ax0 = bflo(self0), ay0 = bfhi(self0);
        float ax1 = 0.f, ay1 = 0.f;
        if (has1) {
            unsigned int self1 = *reinterpret_cast<const unsigned int*>(
                h + (size_t)n1 * 128 + c0);
            ax1 = bflo(self1); ay1 = bfhi(self1);
        }
        float mval0 = (lane < 16) ? mom[(size_t)n0 * 16 + lane] : 0.f;
        float mval1 = (has1 && lane < 16) ? mom[(size_t)n1 * 16 + lane] : 0.f;

        int p0 = s0, p1 = s1;
        // dual phase: 8+8 independent gathers across both streams
        while (p0 + 8 <= e0 && p1 + 8 <= e1) {
            int idxA[8], idxB[8];
#pragma unroll
            for (int j = 0; j < 8; ++j) { idxA[j] = asrc[p0 + j]; idxB[j] = asrc[p1 + j]; }
            unsigned int va[8], vb[8];
#pragma unroll
            for (int j = 0; j < 8; ++j)
                va[j] = *reinterpret_cast<const unsigned int*>(
                    h + (size_t)idxA[j] * 128 + c0);
#pragma unroll
            for (int j = 0; j < 8; ++j)
                vb[j] = *reinterpret_cast<const unsigned int*>(
                    h + (size_t)idxB[j] * 128 + c0);
#pragma unroll
            for (int j = 0; j < 8; ++j) {
                ax0 += bflo(va[j]); ay0 += bfhi(va[j]);
                ax1 += bflo(vb[j]); ay1 += bfhi(vb[j]);
            }
            p0 += 8; p1 += 8;
        }
        // drain stream 0
        for (; p0 + 16 <= e0; p0 += 16) {
            int idx[16];
#pragma unroll
            for (int j = 0; j < 16; ++j) idx[j] = asrc[p0 + j];
            unsigned int vv[16];
#pragma unroll
            for (int j = 0; j < 16; ++j)
                vv[j] = *reinterpret_cast<const unsigned int*>(
                    h + (size_t)idx[j] * 128 + c0);
#pragma unroll
            for (int j = 0; j < 16; ++j) { ax0 += bflo(vv[j]); ay0 += bfhi(vv[j]); }
        }
        for (; p0 < e0; p0 += 8) {
            int idx[8];
#pragma unroll
            for (int j = 0; j < 8; ++j) {
                const int pp = p0 + j;
                idx[j] = (pp < e0) ? asrc[pp] : N;
            }
            unsigned int vv[8];
#pragma unroll
            for (int j = 0; j < 8; ++j)
                vv[j] = *reinterpret_cast<const unsigned int*>(
                    h + (size_t)idx[j] * 128 + c0);
#pragma unroll
            for (int j = 0; j < 8; ++j) { ax0 += bflo(vv[j]); ay0 += bfhi(vv[j]); }
        }
        // drain stream 1
        for (; p1 + 16 <= e1; p1 += 16) {
            int idx[16];
#pragma unroll
            for (int j = 0; j < 16; ++j) idx[j] = asrc[p1 + j];
            unsigned int vv[16];
#pragma unroll
            for (int j = 0; j < 16; ++j)
                vv[j] = *reinterpret_cast<const unsigned int*>(
                    h + (size_t)idx[j] * 128 + c0);
#pragma unroll
            for (int j = 0; j < 16; ++j) { ax1 += bflo(vv[j]); ay1 += bfhi(vv[j]); }
        }
        for (; p1 < e1; p1 += 8) {
            int idx[8];
#pragma unroll
            for (int j = 0; j < 8; ++j) {
                const int pp = p1 + j;
                idx[j] = (pp < e1) ? asrc[pp] : N;
            }
            unsigned int vv[8];
#pragma unroll
            for (int j = 0; j < 8; ++j)
                vv[j] = *reinterpret_cast<const unsigned int*>(
                    h + (size_t)idx[j] * 128 + c0);
#pragma unroll
            for (int j = 0; j < 8; ++j) { ax1 += bflo(vv[j]); ay1 += bfhi(vv[j]); }
        }

        // epilogue node 0
        {
            const float degp1 = (float)(e0 - s0 + 1);
            float d0 = b0 * degp1, d1 = b1 * degp1;
#pragma unroll
            for (int k = 0; k < 16; ++k) {
                const float sk = __shfl(mval0, k);
                d0 += w0[k] * sk; d1 += w1[k] * sk;
            }
            ax0 += d0; ay0 += d1;
            *reinterpret_cast<unsigned int*>(ag + (size_t)n0 * 128 + c0) =
                packbf(ax0, ay0);
        }
        // epilogue node 1
        if (has1) {
            const float degp1 = (float)(e1 - s1 + 1);
            float d0 = b0 * degp1, d1 = b1 * degp1;
#pragma unroll
            for (int k = 0; k < 16; ++k) {
                const float sk = __shfl(mval1, k);
                d0 += w0[k] * sk; d1 += w1[k] * sk;
            }
            ax1 += d0; ay1 += d1;
            *reinterpret_cast<unsigned int*>(ag + (size_t)n1 * 128 + c0) =
                packbf(ax1, ay1);
        }
    }
}

// ---------------------------------------------------------------------------
// BN apply + relu -> bf16 h  (uses precomputed coef)
// ---------------------------------------------------------------------------
__global__ __launch_bounds__(256) void bn_apply_bf16(
    const float* __restrict__ h2, const float* __restrict__ coef,
    unsigned short* __restrict__ h, int total4)
{
    int tid = blockIdx.x * 256 + threadIdx.x;
    int c4 = (tid * 4) & 127;
    float sc[4], sh[4];
#pragma unroll
    for (int j = 0; j < 4; ++j) {
        sc[j] = coef[c4 + j];
        sh[j] = coef[128 + c4 + j];
    }
    int stride = gridDim.x * 256;
    for (int i = tid; i < total4; i += stride) {
        float4v v = reinterpret_cast<const float4v*>(h2)[i];
        float x0 = fmaxf(sc[0] * v[0] + sh[0], 0.f);
        float x1 = fmaxf(sc[1] * v[1] + sh[1], 0.f);
        float x2 = fmaxf(sc[2] * v[2] + sh[2], 0.f);
        float x3 = fmaxf(sc[3] * v[3] + sh[3], 0.f);
        uint2 o; o.x = packbf(x0, x1); o.y = packbf(x2, x3);
        reinterpret_cast<uint2*>(h)[i] = o;
    }
}

// ---------------------------------------------------------------------------
// Pool stage 1: segmented sum over sorted batch keys
// ---------------------------------------------------------------------------
__global__ __launch_bounds__(256) void pool_part(
    const float* __restrict__ h2, const int* __restrict__ batch,
    float* __restrict__ pooled, int N)
{
    const int per = (N + gridDim.x - 1) / gridDim.x;
    const int start = blockIdx.x * per;
    const int end = min(start + per, N);
    if (start >= end) return;
    const int c = threadIdx.x & 127;
    const int sub = threadIdx.x >> 7;
    int g_cur = batch[start];
    float acc = 0.f;
    for (int n = start + sub; n < end; n += 2) {
        int g = batch[n];
        if (g != g_cur) {
            if (acc != 0.f) atomicAdd(&pooled[(size_t)g_cur * 128 + c], acc);
            acc = 0.f; g_cur = g;
        }
        acc += h2[(size_t)n * 128 + c];
    }
    if (acc != 0.f) atomicAdd(&pooled[(size_t)g_cur * 128 + c], acc);
}

// ---------------------------------------------------------------------------
// Pool stage 2: mean + folded final BN affine (coef) + head dot
// ---------------------------------------------------------------------------
__global__ __launch_bounds__(128) void head_final(
    const float* __restrict__ pooled, const int* __restrict__ batch,
    const float* __restrict__ coef, const float* __restrict__ Wp,
    const float* __restrict__ bp, float* __restrict__ out, int N)
{
    const int g = blockIdx.x;
    __shared__ int sb[2];
    if (threadIdx.x < 2) {
        int target = g + threadIdx.x;
        int lo = 0, hi = N;
        while (lo < hi) {
            int mid = (lo + hi) >> 1;
            if (batch[mid] < target) lo = mid + 1; else hi = mid;
        }
        sb[threadIdx.x] = lo;
    }
    __syncthreads();
    const float cntf = fmaxf((float)(sb[1] - sb[0]), 1.f);
    const int c = threadIdx.x;
    float m = pooled[(size_t)g * 128 + c] / cntf;
    float v = (coef[c] * m + coef[128 + c]) * Wp[c];
    const int lane = threadIdx.x & 63;
#pragma unroll
    for (int off = 32; off > 0; off >>= 1) v += __shfl_down(v, off);
    __shared__ float wsum[2];
    if (lane == 0) wsum[threadIdx.x >> 6] = v;
    __syncthreads();
    if (threadIdx.x == 0) out[g] = wsum[0] + wsum[1] + bp[0];
}

// ---------------------------------------------------------------------------
extern "C" void kernel_launch(void* const* d_in, const int* in_sizes, int n_in,
                              void* d_out, int out_size, void* d_ws, size_t ws_size,
                              hipStream_t stream)
{
    const float* x     = (const float*)d_in[0];
    const float* eattr = (const float*)d_in[1];
    const float* W0    = (const float*)d_in[2];
    const float* b0    = (const float*)d_in[3];
    const float* We    = (const float*)d_in[4];
    const float* be    = (const float*)d_in[5];
    const float* W1    = (const float*)d_in[6];
    const float* b1    = (const float*)d_in[7];
    const float* W2    = (const float*)d_in[8];
    const float* b2    = (const float*)d_in[9];
    const float* gamma = (const float*)d_in[10];
    const float* beta  = (const float*)d_in[11];
    const float* Wp    = (const float*)d_in[12];
    const float* bp    = (const float*)d_in[13];
    const int* ei    = (const int*)d_in[14];
    const int* batch = (const int*)d_in[15];

    const int N = in_sizes[0] / 32;   // 50000
    const int E = in_sizes[1] / 16;   // 800000
    const int NB = (N + BNODES - 1) / BNODES;   // 782 buckets

    char* ws = (char*)d_ws;
    size_t off = 0;
    auto alloc = [&](size_t bytes) { char* p = ws + off; off += (bytes + 255) & ~(size_t)255; return p; };
    unsigned short* hb = (unsigned short*)alloc((size_t)(N + 1) * 128 * 2); // +1: zero row
    unsigned short* ag = (unsigned short*)alloc((size_t)N * 128 * 2);
    float* h2 = (float*)alloc((size_t)N * 128 * 4);
    // staging aliases h2 (dead before first fused_mlp write); 12.8MB < 25.6MB
    uint2* staging = (uint2*)h2;
    float* sums2   = (float*)alloc(32 * 256 * 4);
    float* coef    = (float*)alloc(256 * 4);
    float* pooled  = (float*)alloc(NGRAPHS * 128 * 4);
    float* mom     = (float*)alloc((size_t)N * 16 * 4);
    unsigned short* W0bf = (unsigned short*)alloc(128 * 32 * 2);
    unsigned short* W1bf = (unsigned short*)alloc(3 * 256 * 128 * 2);
    unsigned short* W2bf = (unsigned short*)alloc(3 * 128 * 256 * 2);
    int* rowptr   = (int*)alloc(((size_t)N + 1) * 4);
    int* subcnt   = (int*)alloc(((size_t)NB * 8 + 1) * 4);  // +1: ovfcnt tail
    int* ovfcnt   = subcnt + NB * 8;
    int* bucketbase = (int*)alloc(((size_t)NB + 1) * 4);
    uint4* ovfbuf = (uint4*)alloc((size_t)OVFCAP * 16);
    int* asrc     = (int*)alloc((size_t)E * 4);
    int* aeid     = (int*)alloc((size_t)E * 4);

    const dim3 blk(256);
    const int mblocks = (N + 63) / 64;
    const int mtiles = (N + 31) / 32;              // 32-node tiles
    const int fblocks = (mtiles + 2) / 3;          // exactly 3 tiles/block
    const int total4 = N * 32;
    const int eblocks = (E + 255) / 256;
    const float invN = 1.0f / (float)N;

    // --- CSR (bucketed build) + edge-attr moments (once, reused by layers) ---
    hipMemsetAsync(subcnt, 0, ((size_t)NB * 8 + 1) * 4, stream);
    hipMemsetAsync(hb + (size_t)N * 128, 0, 128 * 2, stream);  // zero row N
    edge_scatter<<<dim3(eblocks), blk, 0, stream>>>(
        ei, subcnt, staging, ovfcnt, ovfbuf, E);
    bucket_scan<<<dim3(1), blk, 0, stream>>>(subcnt, bucketbase, NB);
    csr_build<<<dim3(NB), blk, 0, stream>>>(
        subcnt, bucketbase, staging, ovfcnt, ovfbuf, asrc, aeid, rowptr, N, E);
    mom_gather<<<dim3(2048), blk, 0, stream>>>(aeid, rowptr, eattr, mom, N);

    // --- weight pre-conversion ---
    conv_bf16_3<<<dim3(384), blk, 0, stream>>>(
        W0, W0bf, 128 * 32, W1, W1bf, 3 * 256 * 128, W2, W2bf, 3 * 128 * 256);

    // h = bf16(x @ W0^T + b0)
    gemm_bt<32, false, false, true><<<dim3(mblocks, 2), blk, 0, stream>>>(
        x, W0bf, b0, (void*)hb, N, 128);

    for (int l = 0; l < LAYERS; ++l) {
        hipMemsetAsync(sums2, 0, 32 * 256 * 4, stream);
        aggregate_kernel<<<dim3(2048), blk, 0, stream>>>(
            hb, asrc, rowptr, mom, We + l * 128 * 16, be + l * 128, ag, N);
        fused_mlp<<<dim3(fblocks), dim3(512), 0, stream>>>(
            ag, W1bf + l * 256 * 128, b1 + l * 256,
            W2bf + l * 128 * 256, b2 + l * 128, h2, sums2, N, mtiles);
        bn_coef<<<dim3(1), dim3(128), 0, stream>>>(
            sums2, gamma + l * 128, beta + l * 128, coef, invN);
        if (l < LAYERS - 1)
            bn_apply_bf16<<<dim3(1024), blk, 0, stream>>>(h2, coef, hb, total4);
    }

    // --- two-stage mean pool + folded final BN + head ---
    hipMemsetAsync(pooled, 0, NGRAPHS * 128 * 4, stream);
    pool_part<<<dim3(784), blk, 0, stream>>>(h2, batch, pooled, N);
    head_final<<<dim3(NGRAPHS), dim3(128), 0, stream>>>(
        pooled, batch, coef, Wp, bp, (float*)d_out, N);
}

// Round 11
// 475.634 us; speedup vs baseline: 1.0075x; 1.0075x over previous
//
#include <hip/hip_runtime.h>
#include <stdint.h>

#define EMB 128
#define LAYERS 3
#define NGRAPHS 64
#define BN_EPS 1e-5f

// CSR bucket build parameters. NOTE: packing requires N < 65536 (N=50000 here)
// and E < 2^32. Bucket = 64 consecutive dst nodes; 8 XCD-sliced sublists of
// capacity 256 each (mean occupancy 128, 11 sigma headroom); overflow spills
// to a global list (correct but slow path; statistically never taken).
#define BSH 6
#define BNODES 64
#define SUBCAP 256
#define BCAP (8 * SUBCAP + 256)
#define OVFCAP 8192

typedef short short8 __attribute__((ext_vector_type(8)));
typedef float float4v __attribute__((ext_vector_type(4)));
typedef unsigned short ushort4v __attribute__((ext_vector_type(4)));

__device__ __forceinline__ unsigned short f2bf(float f) {
    union { float f; unsigned int i; } v; v.f = f;
    unsigned int x = v.i;
    unsigned int r = x + 0x7FFFu + ((x >> 16) & 1u);
    return (unsigned short)(r >> 16);
}
__device__ __forceinline__ float bflo(unsigned int u) {
    union { unsigned int i; float f; } v; v.i = u << 16; return v.f;
}
__device__ __forceinline__ float bfhi(unsigned int u) {
    union { unsigned int i; float f; } v; v.i = u & 0xffff0000u; return v.f;
}
__device__ __forceinline__ unsigned int packbf(float a, float b) {
    return (unsigned int)f2bf(a) | ((unsigned int)f2bf(b) << 16);
}

// f32 -> bf16 (RNE), three concatenated segments in one dispatch
__global__ __launch_bounds__(256) void conv_bf16_3(
    const float* __restrict__ a, unsigned short* __restrict__ oa, int na,
    const float* __restrict__ b, unsigned short* __restrict__ ob, int nb,
    const float* __restrict__ c, unsigned short* __restrict__ oc, int nc)
{
    int i = blockIdx.x * 256 + threadIdx.x;
    int stride = gridDim.x * 256;
    for (int t = i; t < na + nb + nc; t += stride) {
        if (t < na) oa[t] = f2bf(a[t]);
        else if (t < na + nb) ob[t - na] = f2bf(b[t - na]);
        else oc[t - na - nb] = f2bf(c[t - na - nb]);
    }
}

// ---------------------------------------------------------------------------
// GEMM (input embedding only): C = A[M,K] @ B[Ntot,K]^T + bias
// ---------------------------------------------------------------------------
template<int K, bool A_IS_BF16, bool RELU, bool OUT_BF16>
__global__ __launch_bounds__(256) void gemm_bt(
    const void* __restrict__ Av, const unsigned short* __restrict__ B,
    const float* __restrict__ bias, void* __restrict__ Cv,
    int M, int Ntot)
{
    const int wave = threadIdx.x >> 6;
    const int lane = threadIdx.x & 63;
    const int q    = lane >> 4;
    const int ln   = lane & 15;
    const int m_base = blockIdx.x * 64 + wave * 16;
    const int n_base = blockIdx.y * 64;

    float4v acc[4];
#pragma unroll
    for (int i = 0; i < 4; ++i) acc[i] = (float4v){0.f, 0.f, 0.f, 0.f};

    int mrow = m_base + ln;
    if (mrow >= M) mrow = M - 1;

    const int KSTEPS = K / 32;
#pragma unroll
    for (int ks = 0; ks < KSTEPS; ++ks) {
        const int k0 = ks * 32 + q * 8;
        short8 afrag;
        if constexpr (A_IS_BF16) {
            const unsigned short* A = (const unsigned short*)Av;
            afrag = *reinterpret_cast<const short8*>(A + (size_t)mrow * K + k0);
        } else {
            const float* A = (const float*)Av;
            const float4v* p = reinterpret_cast<const float4v*>(A + (size_t)mrow * K + k0);
            float4v f0 = p[0], f1 = p[1];
            afrag[0] = (short)f2bf(f0[0]); afrag[1] = (short)f2bf(f0[1]);
            afrag[2] = (short)f2bf(f0[2]); afrag[3] = (short)f2bf(f0[3]);
            afrag[4] = (short)f2bf(f1[0]); afrag[5] = (short)f2bf(f1[1]);
            afrag[6] = (short)f2bf(f1[2]); afrag[7] = (short)f2bf(f1[3]);
        }
#pragma unroll
        for (int nt = 0; nt < 4; ++nt) {
            const short8 bfrag = *reinterpret_cast<const short8*>(
                B + (size_t)(n_base + nt * 16 + ln) * K + k0);
            acc[nt] = __builtin_amdgcn_mfma_f32_16x16x32_bf16(afrag, bfrag, acc[nt], 0, 0, 0);
        }
    }

#pragma unroll
    for (int nt = 0; nt < 4; ++nt) {
        const int n = n_base + nt * 16 + ln;
        const float bv = bias[n];
#pragma unroll
        for (int r = 0; r < 4; ++r) {
            const int m = m_base + q * 4 + r;
            if (m < M) {
                float v = acc[nt][r] + bv;
                if constexpr (RELU) v = v > 0.f ? v : 0.f;
                if constexpr (OUT_BF16)
                    ((unsigned short*)Cv)[(size_t)m * Ntot + n] = f2bf(v);
                else
                    ((float*)Cv)[(size_t)m * Ntot + n] = v;
            }
        }
    }
}

// ---------------------------------------------------------------------------
// Fused MLP v6: weights register-resident, 64-node tiles (4 nt sub-tiles),
// one tile per block (782 blocks, 3 blocks/CU co-resident: 51.2KB LDS each).
// Barriers per node halved vs v5; BN atomics per node halved.
// ---------------------------------------------------------------------------
__global__ __launch_bounds__(512) void fused_mlp(
    const unsigned short* __restrict__ ag, const unsigned short* __restrict__ W1,
    const float* __restrict__ b1, const unsigned short* __restrict__ W2,
    const float* __restrict__ b2, float* __restrict__ h2,
    float* __restrict__ sums2, int M, int ntiles)
{
    __shared__ unsigned short ag_lds[64 * 136];
    __shared__ unsigned short Ylds[64 * 264];
    const int tid = threadIdx.x;
    const int wave = tid >> 6, lane = tid & 63;
    const int q = lane >> 4, ln = lane & 15;
    const int k0 = q * 8;
    float* slice = sums2 + (size_t)(blockIdx.x & 31) * 256;

    // --- load resident weight fragments (once per block) ---
    short8 w1f[2][4], w2f[8];
#pragma unroll
    for (int c = 0; c < 2; ++c) {
        const int ct = wave * 2 + c;
#pragma unroll
        for (int ks = 0; ks < 4; ++ks)
            w1f[c][ks] = *reinterpret_cast<const short8*>(
                W1 + (size_t)(ct * 16 + ln) * 128 + ks * 32 + k0);
    }
#pragma unroll
    for (int ks = 0; ks < 8; ++ks)
        w2f[ks] = *reinterpret_cast<const short8*>(
            W2 + (size_t)(wave * 16 + ln) * 256 + ks * 32 + k0);
    float4v b1v[2];
    b1v[0] = *reinterpret_cast<const float4v*>(b1 + (wave * 2) * 16 + q * 4);
    b1v[1] = *reinterpret_cast<const float4v*>(b1 + (wave * 2 + 1) * 16 + q * 4);
    const float4v b2v = *reinterpret_cast<const float4v*>(b2 + wave * 16 + q * 4);

    // staging slots: thread covers nodes nd and nd+32, 8 channels at ch
    const int nd = tid >> 4, ch = (tid & 15) * 8;
    uint4 stg0, stg1;
    {
        int ngA = blockIdx.x * 64 + nd;      if (ngA >= M) ngA = M - 1;
        int ngB = blockIdx.x * 64 + nd + 32; if (ngB >= M) ngB = M - 1;
        stg0 = *reinterpret_cast<const uint4*>(ag + (size_t)ngA * 128 + ch);
        stg1 = *reinterpret_cast<const uint4*>(ag + (size_t)ngB * 128 + ch);
    }

    for (int t = blockIdx.x; t < ntiles; t += gridDim.x) {
        const int nbase = t * 64;
        __syncthreads();   // previous iteration's LDS readers done
        *reinterpret_cast<uint4*>(&ag_lds[nd * 136 + ch]) = stg0;
        *reinterpret_cast<uint4*>(&ag_lds[(nd + 32) * 136 + ch]) = stg1;
        __syncthreads();

        // prefetch next tile while stage-1/2 compute (no-op for 1-tile grids)
        const int tn = t + gridDim.x;
        if (tn < ntiles) {
            int ngA = tn * 64 + nd;      if (ngA >= M) ngA = M - 1;
            int ngB = tn * 64 + nd + 32; if (ngB >= M) ngB = M - 1;
            stg0 = *reinterpret_cast<const uint4*>(ag + (size_t)ngA * 128 + ch);
            stg1 = *reinterpret_cast<const uint4*>(ag + (size_t)ngB * 128 + ch);
        }

        // stage 1: Y^T tile (channels x nodes), per 16-node sub-tile nt
#pragma unroll
        for (int nt = 0; nt < 4; ++nt) {
            short8 agf[4];
#pragma unroll
            for (int ks = 0; ks < 4; ++ks)
                agf[ks] = *reinterpret_cast<const short8*>(
                    &ag_lds[(nt * 16 + ln) * 136 + ks * 32 + k0]);
#pragma unroll
            for (int c = 0; c < 2; ++c) {
                float4v acc = (float4v){0.f, 0.f, 0.f, 0.f};
#pragma unroll
                for (int ks = 0; ks < 4; ++ks)
                    acc = __builtin_amdgcn_mfma_f32_16x16x32_bf16(
                        w1f[c][ks], agf[ks], acc, 0, 0, 0);
                const int c0 = (wave * 2 + c) * 16 + q * 4;
                ushort4v pk;
                pk[0] = f2bf(fmaxf(acc[0] + b1v[c][0], 0.f));
                pk[1] = f2bf(fmaxf(acc[1] + b1v[c][1], 0.f));
                pk[2] = f2bf(fmaxf(acc[2] + b1v[c][2], 0.f));
                pk[3] = f2bf(fmaxf(acc[3] + b1v[c][3], 0.f));
                *reinterpret_cast<ushort4v*>(&Ylds[(nt * 16 + ln) * 264 + c0]) = pk;
            }
        }
        __syncthreads();

        // stage 2: h2 tile + BN partial stats (accumulated over all 4 nt)
        float s[4], s2[4];
#pragma unroll
        for (int r = 0; r < 4; ++r) { s[r] = 0.f; s2[r] = 0.f; }
        const int c0 = wave * 16 + q * 4;
#pragma unroll
        for (int nt = 0; nt < 4; ++nt) {
            short8 yf[8];
#pragma unroll
            for (int ks = 0; ks < 8; ++ks)
                yf[ks] = *reinterpret_cast<const short8*>(
                    &Ylds[(nt * 16 + ln) * 264 + ks * 32 + k0]);
            float4v acc = (float4v){0.f, 0.f, 0.f, 0.f};
#pragma unroll
            for (int ks = 0; ks < 8; ++ks)
                acc = __builtin_amdgcn_mfma_f32_16x16x32_bf16(
                    w2f[ks], yf[ks], acc, 0, 0, 0);
            const int node = nbase + nt * 16 + ln;
            const bool valid = (node < M);
            float4v v;
            v[0] = acc[0] + b2v[0]; v[1] = acc[1] + b2v[1];
            v[2] = acc[2] + b2v[2]; v[3] = acc[3] + b2v[3];
            if (valid)
                *reinterpret_cast<float4v*>(h2 + (size_t)node * 128 + c0) = v;
#pragma unroll
            for (int r = 0; r < 4; ++r) {
                const float x = valid ? v[r] : 0.f;
                s[r] += x; s2[r] += x * x;
            }
        }
#pragma unroll
        for (int off = 1; off < 16; off <<= 1) {
#pragma unroll
            for (int r = 0; r < 4; ++r) {
                s[r]  += __shfl_xor(s[r],  off);
                s2[r] += __shfl_xor(s2[r], off);
            }
        }
        if (ln == 0) {
#pragma unroll
            for (int r = 0; r < 4; ++r) {
                atomicAdd(&slice[c0 + r], s[r]);
                atomicAdd(&slice[128 + c0 + r], s2[r]);
            }
        }
    }
}

// ---------------------------------------------------------------------------
// Fold 32 striped stat slices into per-channel BN (scale, shift)
// ---------------------------------------------------------------------------
__global__ __launch_bounds__(128) void bn_coef(
    const float* __restrict__ sums2, const float* __restrict__ gamma,
    const float* __restrict__ beta, float* __restrict__ coef, float invN)
{
    const int c = threadIdx.x;
    float s = 0.f, ss = 0.f;
    for (int k = 0; k < 32; ++k) {
        s  += sums2[k * 256 + c];
        ss += sums2[k * 256 + 128 + c];
    }
    float mu = s * invN;
    float var = ss * invN - mu * mu;
    float sc = gamma[c] * rsqrtf(fmaxf(var, 0.f) + BN_EPS);
    coef[c] = sc;
    coef[128 + c] = beta[c] - mu * sc;
}

// ---------------------------------------------------------------------------
// CSR build v2: bucketed, write-coalesced, replaces hist+scan+fill.
// ---------------------------------------------------------------------------
__global__ __launch_bounds__(256) void edge_scatter(
    const int* __restrict__ ei, int* __restrict__ subcnt,
    uint2* __restrict__ staging, int* __restrict__ ovfcnt,
    uint4* __restrict__ ovfbuf, int E)
{
    const int sub = blockIdx.x & 7;
    const int e = blockIdx.x * 256 + threadIdx.x;
    if (e >= E) return;
    const unsigned int src = (unsigned int)ei[e];
    const int dst = ei[E + e];
    const int b = dst >> BSH;
    const unsigned int rx = src | ((unsigned int)(dst & (BNODES - 1)) << 16);
    const int sl = b * 8 + sub;
    const int pos = atomicAdd(&subcnt[sl], 1);
    if (pos < SUBCAP) {
        staging[(size_t)sl * SUBCAP + pos] = make_uint2(rx, (unsigned int)e);
    } else {
        int op = atomicAdd(ovfcnt, 1);
        if (op < OVFCAP)
            ovfbuf[op] = make_uint4(rx, (unsigned int)e, (unsigned int)b, 0u);
    }
}

// Exclusive prefix over per-bucket totals (single block).
__global__ __launch_bounds__(256) void bucket_scan(
    const int* __restrict__ subcnt, int* __restrict__ bucketbase, int B)
{
    const int t = threadIdx.x;
    int tot[4]; int mysum = 0;
#pragma unroll
    for (int j = 0; j < 4; ++j) {
        const int b = t * 4 + j;
        int s = 0;
        if (b < B)
            for (int k = 0; k < 8; ++k) s += subcnt[b * 8 + k];
        tot[j] = s; mysum += s;
    }
    const int lane = t & 63, wv = t >> 6;
    int iv = mysum;
#pragma unroll
    for (int off = 1; off < 64; off <<= 1) {
        int u = __shfl_up(iv, off);
        if (lane >= off) iv += u;
    }
    __shared__ int ws[4];
    if (lane == 63) ws[wv] = iv;
    __syncthreads();
    int woff = 0;
    for (int j = 0; j < wv; ++j) woff += ws[j];
    int ex = woff + iv - mysum;
#pragma unroll
    for (int j = 0; j < 4; ++j) {
        const int b = t * 4 + j;
        if (b < B) bucketbase[b] = ex;
        ex += tot[j];
    }
    if (t == 255) bucketbase[B] = ex;
}

// Phase D: one block per bucket. LDS counting-sort -> sequential CSR arrays.
__global__ __launch_bounds__(256) void csr_build(
    const int* __restrict__ subcnt, const int* __restrict__ bucketbase,
    const uint2* __restrict__ staging, const int* __restrict__ ovfcnt,
    const uint4* __restrict__ ovfbuf,
    int* __restrict__ asrc, int* __restrict__ aeid,
    int* __restrict__ rowptr, int N, int E)
{
    __shared__ uint2 recs[BCAP];
    __shared__ int scnt[8], sp[8], cnt[BNODES], rp_s[BNODES], wp2[BNODES];
    __shared__ int totsh;
    const int b = blockIdx.x;
    const int tid = threadIdx.x;
    if (tid < 8) scnt[tid] = min(subcnt[b * 8 + tid], SUBCAP);
    if (tid < BNODES) cnt[tid] = 0;
    __syncthreads();
    if (tid == 0) {
        int a = 0;
        for (int s = 0; s < 8; ++s) { sp[s] = a; a += scnt[s]; }
        totsh = a;
    }
    __syncthreads();
    // load sublists into LDS + per-node counts
    for (int s = 0; s < 8; ++s) {
        const int L = scnt[s];
        const uint2* srcp = staging + (size_t)(b * 8 + s) * SUBCAP;
        for (int i = tid; i < L; i += 256) {
            uint2 r = srcp[i];
            recs[sp[s] + i] = r;
            atomicAdd(&cnt[(r.x >> 16) & (BNODES - 1)], 1);
        }
    }
    __syncthreads();
    // overflow records (statistically never taken; kept for correctness)
    const int ov = min(*ovfcnt, OVFCAP);
    if (ov > 0) {
        for (int i = tid; i < ov; i += 256) {
            uint4 r = ovfbuf[i];
            if ((int)r.z == b) {
                int p = atomicAdd(&totsh, 1);
                if (p < BCAP) {
                    recs[p] = make_uint2(r.x, r.y);
                    atomicAdd(&cnt[(r.x >> 16) & (BNODES - 1)], 1);
                }
            }
        }
    }
    __syncthreads();
    const int total = min(totsh, BCAP);
    // exclusive prefix over 64 per-node counts (wave 0)
    if (tid < BNODES) {
        int v = cnt[tid];
        int iv = v;
#pragma unroll
        for (int off = 1; off < 64; off <<= 1) {
            int u = __shfl_up(iv, off);
            if (tid >= off) iv += u;
        }
        rp_s[tid] = iv - v;
        wp2[tid] = 0;
    }
    __syncthreads();
    const int base = bucketbase[b];
    const int n0 = b * BNODES;
    const int nn = min(BNODES, N - n0);
    if (tid < nn) rowptr[n0 + tid] = base + rp_s[tid];
    if (b == 0 && tid == 0) rowptr[N] = E;
    // scatter within the bucket's contiguous range (L2-coalesced)
    for (int i = tid; i < total; i += 256) {
        uint2 r = recs[i];
        const int d = (r.x >> 16) & (BNODES - 1);
        const int pos = base + rp_s[d] + atomicAdd(&wp2[d], 1);
        asrc[pos] = (int)(r.x & 0xFFFFu);
        aeid[pos] = (int)r.y;
    }
}

// ---------------------------------------------------------------------------
// mom[n][k] = sum of eattr over in-edges (gather, no atomics)
// v2: scalar row bounds, 4-deep gather batches
// ---------------------------------------------------------------------------
__global__ __launch_bounds__(256) void mom_gather(
    const int* __restrict__ aeid, const int* __restrict__ rowptr,
    const float* __restrict__ eattr, float* __restrict__ mom, int N)
{
    const int lane = threadIdx.x & 63;
    const int gwave = (blockIdx.x * 256 + threadIdx.x) >> 6;
    const int nwaves = (gridDim.x * 256) >> 6;
    const int j = lane >> 4, k = lane & 15;
    for (int n = gwave; n < N; n += nwaves) {
        const int s = __builtin_amdgcn_readfirstlane(rowptr[n]);
        const int e = __builtin_amdgcn_readfirstlane(rowptr[n + 1]);
        float acc = 0.f;
        int p = s + j;
        for (; p + 12 < e; p += 16) {
            const int e0 = aeid[p], e1 = aeid[p + 4];
            const int e2 = aeid[p + 8], e3 = aeid[p + 12];
            const float v0 = eattr[(size_t)e0 * 16 + k];
            const float v1 = eattr[(size_t)e1 * 16 + k];
            const float v2 = eattr[(size_t)e2 * 16 + k];
            const float v3 = eattr[(size_t)e3 * 16 + k];
            acc += (v0 + v1) + (v2 + v3);
        }
        for (; p < e; p += 4)
            acc += eattr[(size_t)aeid[p] * 16 + k];
        acc += __shfl_xor(acc, 16);
        acc += __shfl_xor(acc, 32);
        if (lane < 16) mom[(size_t)n * 16 + lane] = acc;
    }
}

// ---------------------------------------------------------------------------
// Gather aggregation over bf16 h:
// ag[n] = bf16( h[n] + Σ_in h[src] + be*(deg+1) + We·mom[n] )
// v6 (r7-proven, structurally floored at ~43us = random-line service ceiling):
// vector index loads (4B asrc), 16-edge full groups, 8-edge zero-row-clamped
// tail groups. r5 (readfirstlane addrs), r8 (shfl-widened gathers), r10
// (dual-stream) all regressed — do not reintroduce.
// ---------------------------------------------------------------------------
__global__ __launch_bounds__(256) void aggregate_kernel(
    const unsigned short* __restrict__ h, const int* __restrict__ asrc,
    const int* __restrict__ rowptr, const float* __restrict__ mom,
    const float* __restrict__ We, const float* __restrict__ be,
    unsigned short* __restrict__ ag, int N)
{
    const int lane = threadIdx.x & 63;
    const int gwave = (blockIdx.x * 256 + threadIdx.x) >> 6;
    const int nwaves = (gridDim.x * 256) >> 6;
    const int c0 = 2 * lane;

    float w0[16], w1[16];
#pragma unroll
    for (int k = 0; k < 16; ++k) {
        w0[k] = We[c0 * 16 + k];
        w1[k] = We[(c0 + 1) * 16 + k];
    }
    const float b0 = be[c0], b1 = be[c0 + 1];

    for (int n = gwave; n < N; n += nwaves) {
        const int s = __builtin_amdgcn_readfirstlane(rowptr[n]);
        const int e = __builtin_amdgcn_readfirstlane(rowptr[n + 1]);
        unsigned int self = *reinterpret_cast<const unsigned int*>(
            h + (size_t)n * 128 + c0);
        float ax = bflo(self), ay = bfhi(self);
        float mval = (lane < 16) ? mom[(size_t)n * 16 + lane] : 0.f;

        int p = s;
        for (; p + 16 <= e; p += 16) {
            int idx[16];
#pragma unroll
            for (int j = 0; j < 16; ++j) idx[j] = asrc[p + j];
            unsigned int vv[16];
#pragma unroll
            for (int j = 0; j < 16; ++j)
                vv[j] = *reinterpret_cast<const unsigned int*>(
                    h + (size_t)idx[j] * 128 + c0);
#pragma unroll
            for (int j = 0; j < 16; ++j) { ax += bflo(vv[j]); ay += bfhi(vv[j]); }
        }
        // tail: 8-edge groups, OOR indices -> zero row N (unmasked accumulate)
        for (; p < e; p += 8) {
            int idx[8];
#pragma unroll
            for (int j = 0; j < 8; ++j) {
                const int pp = p + j;
                idx[j] = (pp < e) ? asrc[pp] : N;
            }
            unsigned int vv[8];
#pragma unroll
            for (int j = 0; j < 8; ++j)
                vv[j] = *reinterpret_cast<const unsigned int*>(
                    h + (size_t)idx[j] * 128 + c0);
#pragma unroll
            for (int j = 0; j < 8; ++j) { ax += bflo(vv[j]); ay += bfhi(vv[j]); }
        }

        const float degp1 = (float)(e - s + 1);
        float d0 = b0 * degp1, d1 = b1 * degp1;
#pragma unroll
        for (int k = 0; k < 16; ++k) {
            const float sk = __shfl(mval, k);
            d0 += w0[k] * sk; d1 += w1[k] * sk;
        }
        ax += d0; ay += d1;
        *reinterpret_cast<unsigned int*>(ag + (size_t)n * 128 + c0) = packbf(ax, ay);
    }
}

// ---------------------------------------------------------------------------
// BN apply + relu -> bf16 h  (uses precomputed coef)
// ---------------------------------------------------------------------------
__global__ __launch_bounds__(256) void bn_apply_bf16(
    const float* __restrict__ h2, const float* __restrict__ coef,
    unsigned short* __restrict__ h, int total4)
{
    int tid = blockIdx.x * 256 + threadIdx.x;
    int c4 = (tid * 4) & 127;
    float sc[4], sh[4];
#pragma unroll
    for (int j = 0; j < 4; ++j) {
        sc[j] = coef[c4 + j];
        sh[j] = coef[128 + c4 + j];
    }
    int stride = gridDim.x * 256;
    for (int i = tid; i < total4; i += stride) {
        float4v v = reinterpret_cast<const float4v*>(h2)[i];
        float x0 = fmaxf(sc[0] * v[0] + sh[0], 0.f);
        float x1 = fmaxf(sc[1] * v[1] + sh[1], 0.f);
        float x2 = fmaxf(sc[2] * v[2] + sh[2], 0.f);
        float x3 = fmaxf(sc[3] * v[3] + sh[3], 0.f);
        uint2 o; o.x = packbf(x0, x1); o.y = packbf(x2, x3);
        reinterpret_cast<uint2*>(h)[i] = o;
    }
}

// ---------------------------------------------------------------------------
// Pool stage 1: segmented sum over sorted batch keys
// ---------------------------------------------------------------------------
__global__ __launch_bounds__(256) void pool_part(
    const float* __restrict__ h2, const int* __restrict__ batch,
    float* __restrict__ pooled, int N)
{
    const int per = (N + gridDim.x - 1) / gridDim.x;
    const int start = blockIdx.x * per;
    const int end = min(start + per, N);
    if (start >= end) return;
    const int c = threadIdx.x & 127;
    const int sub = threadIdx.x >> 7;
    int g_cur = batch[start];
    float acc = 0.f;
    for (int n = start + sub; n < end; n += 2) {
        int g = batch[n];
        if (g != g_cur) {
            if (acc != 0.f) atomicAdd(&pooled[(size_t)g_cur * 128 + c], acc);
            acc = 0.f; g_cur = g;
        }
        acc += h2[(size_t)n * 128 + c];
    }
    if (acc != 0.f) atomicAdd(&pooled[(size_t)g_cur * 128 + c], acc);
}

// ---------------------------------------------------------------------------
// Pool stage 2: mean + folded final BN affine (coef) + head dot
// ---------------------------------------------------------------------------
__global__ __launch_bounds__(128) void head_final(
    const float* __restrict__ pooled, const int* __restrict__ batch,
    const float* __restrict__ coef, const float* __restrict__ Wp,
    const float* __restrict__ bp, float* __restrict__ out, int N)
{
    const int g = blockIdx.x;
    __shared__ int sb[2];
    if (threadIdx.x < 2) {
        int target = g + threadIdx.x;
        int lo = 0, hi = N;
        while (lo < hi) {
            int mid = (lo + hi) >> 1;
            if (batch[mid] < target) lo = mid + 1; else hi = mid;
        }
        sb[threadIdx.x] = lo;
    }
    __syncthreads();
    const float cntf = fmaxf((float)(sb[1] - sb[0]), 1.f);
    const int c = threadIdx.x;
    float m = pooled[(size_t)g * 128 + c] / cntf;
    float v = (coef[c] * m + coef[128 + c]) * Wp[c];
    const int lane = threadIdx.x & 63;
#pragma unroll
    for (int off = 32; off > 0; off >>= 1) v += __shfl_down(v, off);
    __shared__ float wsum[2];
    if (lane == 0) wsum[threadIdx.x >> 6] = v;
    __syncthreads();
    if (threadIdx.x == 0) out[g] = wsum[0] + wsum[1] + bp[0];
}

// ---------------------------------------------------------------------------
extern "C" void kernel_launch(void* const* d_in, const int* in_sizes, int n_in,
                              void* d_out, int out_size, void* d_ws, size_t ws_size,
                              hipStream_t stream)
{
    const float* x     = (const float*)d_in[0];
    const float* eattr = (const float*)d_in[1];
    const float* W0    = (const float*)d_in[2];
    const float* b0    = (const float*)d_in[3];
    const float* We    = (const float*)d_in[4];
    const float* be    = (const float*)d_in[5];
    const float* W1    = (const float*)d_in[6];
    const float* b1    = (const float*)d_in[7];
    const float* W2    = (const float*)d_in[8];
    const float* b2    = (const float*)d_in[9];
    const float* gamma = (const float*)d_in[10];
    const float* beta  = (const float*)d_in[11];
    const float* Wp    = (const float*)d_in[12];
    const float* bp    = (const float*)d_in[13];
    const int* ei    = (const int*)d_in[14];
    const int* batch = (const int*)d_in[15];

    const int N = in_sizes[0] / 32;   // 50000
    const int E = in_sizes[1] / 16;   // 800000
    const int NB = (N + BNODES - 1) / BNODES;   // 782 buckets

    char* ws = (char*)d_ws;
    size_t off = 0;
    auto alloc = [&](size_t bytes) { char* p = ws + off; off += (bytes + 255) & ~(size_t)255; return p; };
    unsigned short* hb = (unsigned short*)alloc((size_t)(N + 1) * 128 * 2); // +1: zero row
    unsigned short* ag = (unsigned short*)alloc((size_t)N * 128 * 2);
    float* h2 = (float*)alloc((size_t)N * 128 * 4);
    // staging aliases h2 (dead before first fused_mlp write); 12.8MB < 25.6MB
    uint2* staging = (uint2*)h2;
    float* sums2   = (float*)alloc(32 * 256 * 4);
    float* coef    = (float*)alloc(256 * 4);
    float* pooled  = (float*)alloc(NGRAPHS * 128 * 4);
    float* mom     = (float*)alloc((size_t)N * 16 * 4);
    unsigned short* W0bf = (unsigned short*)alloc(128 * 32 * 2);
    unsigned short* W1bf = (unsigned short*)alloc(3 * 256 * 128 * 2);
    unsigned short* W2bf = (unsigned short*)alloc(3 * 128 * 256 * 2);
    int* rowptr   = (int*)alloc(((size_t)N + 1) * 4);
    int* subcnt   = (int*)alloc(((size_t)NB * 8 + 1) * 4);  // +1: ovfcnt tail
    int* ovfcnt   = subcnt + NB * 8;
    int* bucketbase = (int*)alloc(((size_t)NB + 1) * 4);
    uint4* ovfbuf = (uint4*)alloc((size_t)OVFCAP * 16);
    int* asrc     = (int*)alloc((size_t)E * 4);
    int* aeid     = (int*)alloc((size_t)E * 4);

    const dim3 blk(256);
    const int mblocks = (N + 63) / 64;
    const int mtiles64 = (N + 63) / 64;            // 64-node tiles (782)
    const int total4 = N * 32;
    const int eblocks = (E + 255) / 256;
    const float invN = 1.0f / (float)N;

    // --- CSR (bucketed build) + edge-attr moments (once, reused by layers) ---
    hipMemsetAsync(subcnt, 0, ((size_t)NB * 8 + 1) * 4, stream);
    hipMemsetAsync(hb + (size_t)N * 128, 0, 128 * 2, stream);  // zero row N
    edge_scatter<<<dim3(eblocks), blk, 0, stream>>>(
        ei, subcnt, staging, ovfcnt, ovfbuf, E);
    bucket_scan<<<dim3(1), blk, 0, stream>>>(subcnt, bucketbase, NB);
    csr_build<<<dim3(NB), blk, 0, stream>>>(
        subcnt, bucketbase, staging, ovfcnt, ovfbuf, asrc, aeid, rowptr, N, E);
    mom_gather<<<dim3(2048), blk, 0, stream>>>(aeid, rowptr, eattr, mom, N);

    // --- weight pre-conversion ---
    conv_bf16_3<<<dim3(384), blk, 0, stream>>>(
        W0, W0bf, 128 * 32, W1, W1bf, 3 * 256 * 128, W2, W2bf, 3 * 128 * 256);

    // h = bf16(x @ W0^T + b0)
    gemm_bt<32, false, false, true><<<dim3(mblocks, 2), blk, 0, stream>>>(
        x, W0bf, b0, (void*)hb, N, 128);

    for (int l = 0; l < LAYERS; ++l) {
        hipMemsetAsync(sums2, 0, 32 * 256 * 4, stream);
        aggregate_kernel<<<dim3(2048), blk, 0, stream>>>(
            hb, asrc, rowptr, mom, We + l * 128 * 16, be + l * 128, ag, N);
        fused_mlp<<<dim3(mtiles64), dim3(512), 0, stream>>>(
            ag, W1bf + l * 256 * 128, b1 + l * 256,
            W2bf + l * 128 * 256, b2 + l * 128, h2, sums2, N, mtiles64);
        bn_coef<<<dim3(1), dim3(128), 0, stream>>>(
            sums2, gamma + l * 128, beta + l * 128, coef, invN);
        if (l < LAYERS - 1)
            bn_apply_bf16<<<dim3(1024), blk, 0, stream>>>(h2, coef, hb, total4);
    }

    // --- two-stage mean pool + folded final BN + head ---
    hipMemsetAsync(pooled, 0, NGRAPHS * 128 * 4, stream);
    pool_part<<<dim3(784), blk, 0, stream>>>(h2, batch, pooled, N);
    head_final<<<dim3(NGRAPHS), dim3(128), 0, stream>>>(
        pooled, batch, coef, Wp, bp, (float*)d_out, N);
}

// Round 12
// 461.484 us; speedup vs baseline: 1.0384x; 1.0307x over previous
//
#include <hip/hip_runtime.h>
#include <stdint.h>

#define EMB 128
#define LAYERS 3
#define NGRAPHS 64
#define BN_EPS 1e-5f

// CSR bucket build parameters. NOTE: packing requires N < 65536 (N=50000 here)
// and E < 2^32. Bucket = 64 consecutive dst nodes; 8 XCD-sliced sublists of
// capacity 256 each (mean occupancy 128, 11 sigma headroom); overflow spills
// to a global list (correct but slow path; statistically never taken).
#define BSH 6
#define BNODES 64
#define SUBCAP 256
#define BCAP (8 * SUBCAP + 256)
#define OVFCAP 8192

typedef short short8 __attribute__((ext_vector_type(8)));
typedef float float4v __attribute__((ext_vector_type(4)));
typedef unsigned short ushort4v __attribute__((ext_vector_type(4)));

__device__ __forceinline__ unsigned short f2bf(float f) {
    union { float f; unsigned int i; } v; v.f = f;
    unsigned int x = v.i;
    unsigned int r = x + 0x7FFFu + ((x >> 16) & 1u);
    return (unsigned short)(r >> 16);
}
__device__ __forceinline__ float bflo(unsigned int u) {
    union { unsigned int i; float f; } v; v.i = u << 16; return v.f;
}
__device__ __forceinline__ float bfhi(unsigned int u) {
    union { unsigned int i; float f; } v; v.i = u & 0xffff0000u; return v.f;
}
__device__ __forceinline__ unsigned int packbf(float a, float b) {
    return (unsigned int)f2bf(a) | ((unsigned int)f2bf(b) << 16);
}

// f32 -> bf16 (RNE), three concatenated segments in one dispatch.
// Also zeroes the 128-entry zero-row (folds away a memset launch).
__global__ __launch_bounds__(256) void conv_bf16_3(
    const float* __restrict__ a, unsigned short* __restrict__ oa, int na,
    const float* __restrict__ b, unsigned short* __restrict__ ob, int nb,
    const float* __restrict__ c, unsigned short* __restrict__ oc, int nc,
    unsigned short* __restrict__ zrow)
{
    int i = blockIdx.x * 256 + threadIdx.x;
    if (i < 128) zrow[i] = 0;
    int stride = gridDim.x * 256;
    for (int t = i; t < na + nb + nc; t += stride) {
        if (t < na) oa[t] = f2bf(a[t]);
        else if (t < na + nb) ob[t - na] = f2bf(b[t - na]);
        else oc[t - na - nb] = f2bf(c[t - na - nb]);
    }
}

// ---------------------------------------------------------------------------
// GEMM (input embedding only): C = A[M,K] @ B[Ntot,K]^T + bias
// ---------------------------------------------------------------------------
template<int K, bool A_IS_BF16, bool RELU, bool OUT_BF16>
__global__ __launch_bounds__(256) void gemm_bt(
    const void* __restrict__ Av, const unsigned short* __restrict__ B,
    const float* __restrict__ bias, void* __restrict__ Cv,
    int M, int Ntot)
{
    const int wave = threadIdx.x >> 6;
    const int lane = threadIdx.x & 63;
    const int q    = lane >> 4;
    const int ln   = lane & 15;
    const int m_base = blockIdx.x * 64 + wave * 16;
    const int n_base = blockIdx.y * 64;

    float4v acc[4];
#pragma unroll
    for (int i = 0; i < 4; ++i) acc[i] = (float4v){0.f, 0.f, 0.f, 0.f};

    int mrow = m_base + ln;
    if (mrow >= M) mrow = M - 1;

    const int KSTEPS = K / 32;
#pragma unroll
    for (int ks = 0; ks < KSTEPS; ++ks) {
        const int k0 = ks * 32 + q * 8;
        short8 afrag;
        if constexpr (A_IS_BF16) {
            const unsigned short* A = (const unsigned short*)Av;
            afrag = *reinterpret_cast<const short8*>(A + (size_t)mrow * K + k0);
        } else {
            const float* A = (const float*)Av;
            const float4v* p = reinterpret_cast<const float4v*>(A + (size_t)mrow * K + k0);
            float4v f0 = p[0], f1 = p[1];
            afrag[0] = (short)f2bf(f0[0]); afrag[1] = (short)f2bf(f0[1]);
            afrag[2] = (short)f2bf(f0[2]); afrag[3] = (short)f2bf(f0[3]);
            afrag[4] = (short)f2bf(f1[0]); afrag[5] = (short)f2bf(f1[1]);
            afrag[6] = (short)f2bf(f1[2]); afrag[7] = (short)f2bf(f1[3]);
        }
#pragma unroll
        for (int nt = 0; nt < 4; ++nt) {
            const short8 bfrag = *reinterpret_cast<const short8*>(
                B + (size_t)(n_base + nt * 16 + ln) * K + k0);
            acc[nt] = __builtin_amdgcn_mfma_f32_16x16x32_bf16(afrag, bfrag, acc[nt], 0, 0, 0);
        }
    }

#pragma unroll
    for (int nt = 0; nt < 4; ++nt) {
        const int n = n_base + nt * 16 + ln;
        const float bv = bias[n];
#pragma unroll
        for (int r = 0; r < 4; ++r) {
            const int m = m_base + q * 4 + r;
            if (m < M) {
                float v = acc[nt][r] + bv;
                if constexpr (RELU) v = v > 0.f ? v : 0.f;
                if constexpr (OUT_BF16)
                    ((unsigned short*)Cv)[(size_t)m * Ntot + n] = f2bf(v);
                else
                    ((float*)Cv)[(size_t)m * Ntot + n] = v;
            }
        }
    }
}

// ---------------------------------------------------------------------------
// Fused MLP v5 (r7-proven best): weights register-resident, 32-node tiles,
// next-tile register prefetch. 64-node tiles regressed (r11, LDS-occupancy);
// 16-node tiles regressed (r3, barrier-bound). Do not change tile size.
// ---------------------------------------------------------------------------
__global__ __launch_bounds__(512) void fused_mlp(
    const unsigned short* __restrict__ ag, const unsigned short* __restrict__ W1,
    const float* __restrict__ b1, const unsigned short* __restrict__ W2,
    const float* __restrict__ b2, float* __restrict__ h2,
    float* __restrict__ sums2, int M, int ntiles)
{
    __shared__ unsigned short ag_lds[32 * 136];
    __shared__ unsigned short Ylds[32 * 264];
    const int tid = threadIdx.x;
    const int wave = tid >> 6, lane = tid & 63;
    const int q = lane >> 4, ln = lane & 15;
    const int k0 = q * 8;
    float* slice = sums2 + (size_t)(blockIdx.x & 31) * 256;

    // --- load resident weight fragments (once per block) ---
    short8 w1f[2][4], w2f[8];
#pragma unroll
    for (int c = 0; c < 2; ++c) {
        const int ct = wave * 2 + c;
#pragma unroll
        for (int ks = 0; ks < 4; ++ks)
            w1f[c][ks] = *reinterpret_cast<const short8*>(
                W1 + (size_t)(ct * 16 + ln) * 128 + ks * 32 + k0);
    }
#pragma unroll
    for (int ks = 0; ks < 8; ++ks)
        w2f[ks] = *reinterpret_cast<const short8*>(
            W2 + (size_t)(wave * 16 + ln) * 256 + ks * 32 + k0);
    float4v b1v[2];
    b1v[0] = *reinterpret_cast<const float4v*>(b1 + (wave * 2) * 16 + q * 4);
    b1v[1] = *reinterpret_cast<const float4v*>(b1 + (wave * 2 + 1) * 16 + q * 4);
    const float4v b2v = *reinterpret_cast<const float4v*>(b2 + wave * 16 + q * 4);

    // staging slot for this thread: node nd, 8 channels at ch
    const int nd = tid >> 4, ch = (tid & 15) * 8;
    uint4 stage;
    {
        int ng = blockIdx.x * 32 + nd; if (ng >= M) ng = M - 1;
        stage = *reinterpret_cast<const uint4*>(ag + (size_t)ng * 128 + ch);
    }

    for (int t = blockIdx.x; t < ntiles; t += gridDim.x) {
        const int nbase = t * 32;
        __syncthreads();   // previous iteration's LDS readers done
        *reinterpret_cast<uint4*>(&ag_lds[nd * 136 + ch]) = stage;
        __syncthreads();

        // prefetch next tile while stage-1/2 compute
        const int tn = t + gridDim.x;
        if (tn < ntiles) {
            int ng = tn * 32 + nd; if (ng >= M) ng = M - 1;
            stage = *reinterpret_cast<const uint4*>(ag + (size_t)ng * 128 + ch);
        }

        // stage 1: Y^T tile (channels x nodes), per 16-node sub-tile nt
#pragma unroll
        for (int nt = 0; nt < 2; ++nt) {
            short8 agf[4];
#pragma unroll
            for (int ks = 0; ks < 4; ++ks)
                agf[ks] = *reinterpret_cast<const short8*>(
                    &ag_lds[(nt * 16 + ln) * 136 + ks * 32 + k0]);
#pragma unroll
            for (int c = 0; c < 2; ++c) {
                float4v acc = (float4v){0.f, 0.f, 0.f, 0.f};
#pragma unroll
                for (int ks = 0; ks < 4; ++ks)
                    acc = __builtin_amdgcn_mfma_f32_16x16x32_bf16(
                        w1f[c][ks], agf[ks], acc, 0, 0, 0);
                const int c0 = (wave * 2 + c) * 16 + q * 4;
                ushort4v pk;
                pk[0] = f2bf(fmaxf(acc[0] + b1v[c][0], 0.f));
                pk[1] = f2bf(fmaxf(acc[1] + b1v[c][1], 0.f));
                pk[2] = f2bf(fmaxf(acc[2] + b1v[c][2], 0.f));
                pk[3] = f2bf(fmaxf(acc[3] + b1v[c][3], 0.f));
                *reinterpret_cast<ushort4v*>(&Ylds[(nt * 16 + ln) * 264 + c0]) = pk;
            }
        }
        __syncthreads();

        // stage 2: h2 tile + BN partial stats (accumulated over both nt)
        float s[4], s2[4];
#pragma unroll
        for (int r = 0; r < 4; ++r) { s[r] = 0.f; s2[r] = 0.f; }
        const int c0 = wave * 16 + q * 4;
#pragma unroll
        for (int nt = 0; nt < 2; ++nt) {
            short8 yf[8];
#pragma unroll
            for (int ks = 0; ks < 8; ++ks)
                yf[ks] = *reinterpret_cast<const short8*>(
                    &Ylds[(nt * 16 + ln) * 264 + ks * 32 + k0]);
            float4v acc = (float4v){0.f, 0.f, 0.f, 0.f};
#pragma unroll
            for (int ks = 0; ks < 8; ++ks)
                acc = __builtin_amdgcn_mfma_f32_16x16x32_bf16(
                    w2f[ks], yf[ks], acc, 0, 0, 0);
            const int node = nbase + nt * 16 + ln;
            const bool valid = (node < M);
            float4v v;
            v[0] = acc[0] + b2v[0]; v[1] = acc[1] + b2v[1];
            v[2] = acc[2] + b2v[2]; v[3] = acc[3] + b2v[3];
            if (valid)
                *reinterpret_cast<float4v*>(h2 + (size_t)node * 128 + c0) = v;
#pragma unroll
            for (int r = 0; r < 4; ++r) {
                const float x = valid ? v[r] : 0.f;
                s[r] += x; s2[r] += x * x;
            }
        }
#pragma unroll
        for (int off = 1; off < 16; off <<= 1) {
#pragma unroll
            for (int r = 0; r < 4; ++r) {
                s[r]  += __shfl_xor(s[r],  off);
                s2[r] += __shfl_xor(s2[r], off);
            }
        }
        if (ln == 0) {
#pragma unroll
            for (int r = 0; r < 4; ++r) {
                atomicAdd(&slice[c0 + r], s[r]);
                atomicAdd(&slice[128 + c0 + r], s2[r]);
            }
        }
    }
}

// ---------------------------------------------------------------------------
// Fold 32 striped stat slices into per-channel BN (scale, shift).
// Also zeroes sums2 after reading (removes the per-layer memset launch).
// ---------------------------------------------------------------------------
__global__ __launch_bounds__(128) void bn_coef(
    float* __restrict__ sums2, const float* __restrict__ gamma,
    const float* __restrict__ beta, float* __restrict__ coef, float invN)
{
    const int c = threadIdx.x;
    float s = 0.f, ss = 0.f;
    for (int k = 0; k < 32; ++k) {
        s  += sums2[k * 256 + c];
        ss += sums2[k * 256 + 128 + c];
    }
    for (int k = 0; k < 32; ++k) {
        sums2[k * 256 + c] = 0.f;
        sums2[k * 256 + 128 + c] = 0.f;
    }
    float mu = s * invN;
    float var = ss * invN - mu * mu;
    float sc = gamma[c] * rsqrtf(fmaxf(var, 0.f) + BN_EPS);
    coef[c] = sc;
    coef[128 + c] = beta[c] - mu * sc;
}

// ---------------------------------------------------------------------------
// CSR build v2: bucketed, write-coalesced, replaces hist+scan+fill.
// ---------------------------------------------------------------------------
__global__ __launch_bounds__(256) void edge_scatter(
    const int* __restrict__ ei, int* __restrict__ subcnt,
    uint2* __restrict__ staging, int* __restrict__ ovfcnt,
    uint4* __restrict__ ovfbuf, int E)
{
    const int sub = blockIdx.x & 7;
    const int e = blockIdx.x * 256 + threadIdx.x;
    if (e >= E) return;
    const unsigned int src = (unsigned int)ei[e];
    const int dst = ei[E + e];
    const int b = dst >> BSH;
    const unsigned int rx = src | ((unsigned int)(dst & (BNODES - 1)) << 16);
    const int sl = b * 8 + sub;
    const int pos = atomicAdd(&subcnt[sl], 1);
    if (pos < SUBCAP) {
        staging[(size_t)sl * SUBCAP + pos] = make_uint2(rx, (unsigned int)e);
    } else {
        int op = atomicAdd(ovfcnt, 1);
        if (op < OVFCAP)
            ovfbuf[op] = make_uint4(rx, (unsigned int)e, (unsigned int)b, 0u);
    }
}

// Exclusive prefix over per-bucket totals (single block).
__global__ __launch_bounds__(256) void bucket_scan(
    const int* __restrict__ subcnt, int* __restrict__ bucketbase, int B)
{
    const int t = threadIdx.x;
    int tot[4]; int mysum = 0;
#pragma unroll
    for (int j = 0; j < 4; ++j) {
        const int b = t * 4 + j;
        int s = 0;
        if (b < B)
            for (int k = 0; k < 8; ++k) s += subcnt[b * 8 + k];
        tot[j] = s; mysum += s;
    }
    const int lane = t & 63, wv = t >> 6;
    int iv = mysum;
#pragma unroll
    for (int off = 1; off < 64; off <<= 1) {
        int u = __shfl_up(iv, off);
        if (lane >= off) iv += u;
    }
    __shared__ int ws[4];
    if (lane == 63) ws[wv] = iv;
    __syncthreads();
    int woff = 0;
    for (int j = 0; j < wv; ++j) woff += ws[j];
    int ex = woff + iv - mysum;
#pragma unroll
    for (int j = 0; j < 4; ++j) {
        const int b = t * 4 + j;
        if (b < B) bucketbase[b] = ex;
        ex += tot[j];
    }
    if (t == 255) bucketbase[B] = ex;
}

// Phase D: one block per bucket. LDS counting-sort -> sequential CSR arrays.
__global__ __launch_bounds__(256) void csr_build(
    const int* __restrict__ subcnt, const int* __restrict__ bucketbase,
    const uint2* __restrict__ staging, const int* __restrict__ ovfcnt,
    const uint4* __restrict__ ovfbuf,
    int* __restrict__ asrc, int* __restrict__ aeid,
    int* __restrict__ rowptr, int N, int E)
{
    __shared__ uint2 recs[BCAP];
    __shared__ int scnt[8], sp[8], cnt[BNODES], rp_s[BNODES], wp2[BNODES];
    __shared__ int totsh;
    const int b = blockIdx.x;
    const int tid = threadIdx.x;
    if (tid < 8) scnt[tid] = min(subcnt[b * 8 + tid], SUBCAP);
    if (tid < BNODES) cnt[tid] = 0;
    __syncthreads();
    if (tid == 0) {
        int a = 0;
        for (int s = 0; s < 8; ++s) { sp[s] = a; a += scnt[s]; }
        totsh = a;
    }
    __syncthreads();
    // load sublists into LDS + per-node counts
    for (int s = 0; s < 8; ++s) {
        const int L = scnt[s];
        const uint2* srcp = staging + (size_t)(b * 8 + s) * SUBCAP;
        for (int i = tid; i < L; i += 256) {
            uint2 r = srcp[i];
            recs[sp[s] + i] = r;
            atomicAdd(&cnt[(r.x >> 16) & (BNODES - 1)], 1);
        }
    }
    __syncthreads();
    // overflow records (statistically never taken; kept for correctness)
    const int ov = min(*ovfcnt, OVFCAP);
    if (ov > 0) {
        for (int i = tid; i < ov; i += 256) {
            uint4 r = ovfbuf[i];
            if ((int)r.z == b) {
                int p = atomicAdd(&totsh, 1);
                if (p < BCAP) {
                    recs[p] = make_uint2(r.x, r.y);
                    atomicAdd(&cnt[(r.x >> 16) & (BNODES - 1)], 1);
                }
            }
        }
    }
    __syncthreads();
    const int total = min(totsh, BCAP);
    // exclusive prefix over 64 per-node counts (wave 0)
    if (tid < BNODES) {
        int v = cnt[tid];
        int iv = v;
#pragma unroll
        for (int off = 1; off < 64; off <<= 1) {
            int u = __shfl_up(iv, off);
            if (tid >= off) iv += u;
        }
        rp_s[tid] = iv - v;
        wp2[tid] = 0;
    }
    __syncthreads();
    const int base = bucketbase[b];
    const int n0 = b * BNODES;
    const int nn = min(BNODES, N - n0);
    if (tid < nn) rowptr[n0 + tid] = base + rp_s[tid];
    if (b == 0 && tid == 0) rowptr[N] = E;
    // scatter within the bucket's contiguous range (L2-coalesced)
    for (int i = tid; i < total; i += 256) {
        uint2 r = recs[i];
        const int d = (r.x >> 16) & (BNODES - 1);
        const int pos = base + rp_s[d] + atomicAdd(&wp2[d], 1);
        asrc[pos] = (int)(r.x & 0xFFFFu);
        aeid[pos] = (int)r.y;
    }
}

// ---------------------------------------------------------------------------
// mom[n][k] = sum of eattr over in-edges (gather, no atomics)
// v2: scalar row bounds, 4-deep gather batches
// ---------------------------------------------------------------------------
__global__ __launch_bounds__(256) void mom_gather(
    const int* __restrict__ aeid, const int* __restrict__ rowptr,
    const float* __restrict__ eattr, float* __restrict__ mom, int N)
{
    const int lane = threadIdx.x & 63;
    const int gwave = (blockIdx.x * 256 + threadIdx.x) >> 6;
    const int nwaves = (gridDim.x * 256) >> 6;
    const int j = lane >> 4, k = lane & 15;
    for (int n = gwave; n < N; n += nwaves) {
        const int s = __builtin_amdgcn_readfirstlane(rowptr[n]);
        const int e = __builtin_amdgcn_readfirstlane(rowptr[n + 1]);
        float acc = 0.f;
        int p = s + j;
        for (; p + 12 < e; p += 16) {
            const int e0 = aeid[p], e1 = aeid[p + 4];
            const int e2 = aeid[p + 8], e3 = aeid[p + 12];
            const float v0 = eattr[(size_t)e0 * 16 + k];
            const float v1 = eattr[(size_t)e1 * 16 + k];
            const float v2 = eattr[(size_t)e2 * 16 + k];
            const float v3 = eattr[(size_t)e3 * 16 + k];
            acc += (v0 + v1) + (v2 + v3);
        }
        for (; p < e; p += 4)
            acc += eattr[(size_t)aeid[p] * 16 + k];
        acc += __shfl_xor(acc, 16);
        acc += __shfl_xor(acc, 32);
        if (lane < 16) mom[(size_t)n * 16 + lane] = acc;
    }
}

// ---------------------------------------------------------------------------
// Gather aggregation over bf16 h:
// ag[n] = bf16( h[n] + Σ_in h[src] + be*(deg+1) + We·mom[n] )
// r7-proven, structurally floored at ~43us (= random 64B-line service ceiling,
// ~2TB/s): vector index loads (4B asrc), 16-edge full groups, 8-edge zero-row-
// clamped tail groups. r5 (readfirstlane addrs), r8 (shfl-widened gathers),
// r10 (dual-stream) all regressed — do not reintroduce.
// ---------------------------------------------------------------------------
__global__ __launch_bounds__(256) void aggregate_kernel(
    const unsigned short* __restrict__ h, const int* __restrict__ asrc,
    const int* __restrict__ rowptr, const float* __restrict__ mom,
    const float* __restrict__ We, const float* __restrict__ be,
    unsigned short* __restrict__ ag, int N)
{
    const int lane = threadIdx.x & 63;
    const int gwave = (blockIdx.x * 256 + threadIdx.x) >> 6;
    const int nwaves = (gridDim.x * 256) >> 6;
    const int c0 = 2 * lane;

    float w0[16], w1[16];
#pragma unroll
    for (int k = 0; k < 16; ++k) {
        w0[k] = We[c0 * 16 + k];
        w1[k] = We[(c0 + 1) * 16 + k];
    }
    const float b0 = be[c0], b1 = be[c0 + 1];

    for (int n = gwave; n < N; n += nwaves) {
        const int s = __builtin_amdgcn_readfirstlane(rowptr[n]);
        const int e = __builtin_amdgcn_readfirstlane(rowptr[n + 1]);
        unsigned int self = *reinterpret_cast<const unsigned int*>(
            h + (size_t)n * 128 + c0);
        float ax = bflo(self), ay = bfhi(self);
        float mval = (lane < 16) ? mom[(size_t)n * 16 + lane] : 0.f;

        int p = s;
        for (; p + 16 <= e; p += 16) {
            int idx[16];
#pragma unroll
            for (int j = 0; j < 16; ++j) idx[j] = asrc[p + j];
            unsigned int vv[16];
#pragma unroll
            for (int j = 0; j < 16; ++j)
                vv[j] = *reinterpret_cast<const unsigned int*>(
                    h + (size_t)idx[j] * 128 + c0);
#pragma unroll
            for (int j = 0; j < 16; ++j) { ax += bflo(vv[j]); ay += bfhi(vv[j]); }
        }
        // tail: 8-edge groups, OOR indices -> zero row N (unmasked accumulate)
        for (; p < e; p += 8) {
            int idx[8];
#pragma unroll
            for (int j = 0; j < 8; ++j) {
                const int pp = p + j;
                idx[j] = (pp < e) ? asrc[pp] : N;
            }
            unsigned int vv[8];
#pragma unroll
            for (int j = 0; j < 8; ++j)
                vv[j] = *reinterpret_cast<const unsigned int*>(
                    h + (size_t)idx[j] * 128 + c0);
#pragma unroll
            for (int j = 0; j < 8; ++j) { ax += bflo(vv[j]); ay += bfhi(vv[j]); }
        }

        const float degp1 = (float)(e - s + 1);
        float d0 = b0 * degp1, d1 = b1 * degp1;
#pragma unroll
        for (int k = 0; k < 16; ++k) {
            const float sk = __shfl(mval, k);
            d0 += w0[k] * sk; d1 += w1[k] * sk;
        }
        ax += d0; ay += d1;
        *reinterpret_cast<unsigned int*>(ag + (size_t)n * 128 + c0) = packbf(ax, ay);
    }
}

// ---------------------------------------------------------------------------
// BN apply + relu -> bf16 h  (uses precomputed coef)
// ---------------------------------------------------------------------------
__global__ __launch_bounds__(256) void bn_apply_bf16(
    const float* __restrict__ h2, const float* __restrict__ coef,
    unsigned short* __restrict__ h, int total4)
{
    int tid = blockIdx.x * 256 + threadIdx.x;
    int c4 = (tid * 4) & 127;
    float sc[4], sh[4];
#pragma unroll
    for (int j = 0; j < 4; ++j) {
        sc[j] = coef[c4 + j];
        sh[j] = coef[128 + c4 + j];
    }
    int stride = gridDim.x * 256;
    for (int i = tid; i < total4; i += stride) {
        float4v v = reinterpret_cast<const float4v*>(h2)[i];
        float x0 = fmaxf(sc[0] * v[0] + sh[0], 0.f);
        float x1 = fmaxf(sc[1] * v[1] + sh[1], 0.f);
        float x2 = fmaxf(sc[2] * v[2] + sh[2], 0.f);
        float x3 = fmaxf(sc[3] * v[3] + sh[3], 0.f);
        uint2 o; o.x = packbf(x0, x1); o.y = packbf(x2, x3);
        reinterpret_cast<uint2*>(h)[i] = o;
    }
}

// ---------------------------------------------------------------------------
// Pool stage 1: segmented sum over sorted batch keys
// ---------------------------------------------------------------------------
__global__ __launch_bounds__(256) void pool_part(
    const float* __restrict__ h2, const int* __restrict__ batch,
    float* __restrict__ pooled, int N)
{
    const int per = (N + gridDim.x - 1) / gridDim.x;
    const int start = blockIdx.x * per;
    const int end = min(start + per, N);
    if (start >= end) return;
    const int c = threadIdx.x & 127;
    const int sub = threadIdx.x >> 7;
    int g_cur = batch[start];
    float acc = 0.f;
    for (int n = start + sub; n < end; n += 2) {
        int g = batch[n];
        if (g != g_cur) {
            if (acc != 0.f) atomicAdd(&pooled[(size_t)g_cur * 128 + c], acc);
            acc = 0.f; g_cur = g;
        }
        acc += h2[(size_t)n * 128 + c];
    }
    if (acc != 0.f) atomicAdd(&pooled[(size_t)g_cur * 128 + c], acc);
}

// ---------------------------------------------------------------------------
// Pool stage 2: mean + folded final BN affine (coef) + head dot
// ---------------------------------------------------------------------------
__global__ __launch_bounds__(128) void head_final(
    const float* __restrict__ pooled, const int* __restrict__ batch,
    const float* __restrict__ coef, const float* __restrict__ Wp,
    const float* __restrict__ bp, float* __restrict__ out, int N)
{
    const int g = blockIdx.x;
    __shared__ int sb[2];
    if (threadIdx.x < 2) {
        int target = g + threadIdx.x;
        int lo = 0, hi = N;
        while (lo < hi) {
            int mid = (lo + hi) >> 1;
            if (batch[mid] < target) lo = mid + 1; else hi = mid;
        }
        sb[threadIdx.x] = lo;
    }
    __syncthreads();
    const float cntf = fmaxf((float)(sb[1] - sb[0]), 1.f);
    const int c = threadIdx.x;
    float m = pooled[(size_t)g * 128 + c] / cntf;
    float v = (coef[c] * m + coef[128 + c]) * Wp[c];
    const int lane = threadIdx.x & 63;
#pragma unroll
    for (int off = 32; off > 0; off >>= 1) v += __shfl_down(v, off);
    __shared__ float wsum[2];
    if (lane == 0) wsum[threadIdx.x >> 6] = v;
    __syncthreads();
    if (threadIdx.x == 0) out[g] = wsum[0] + wsum[1] + bp[0];
}

// ---------------------------------------------------------------------------
extern "C" void kernel_launch(void* const* d_in, const int* in_sizes, int n_in,
                              void* d_out, int out_size, void* d_ws, size_t ws_size,
                              hipStream_t stream)
{
    const float* x     = (const float*)d_in[0];
    const float* eattr = (const float*)d_in[1];
    const float* W0    = (const float*)d_in[2];
    const float* b0    = (const float*)d_in[3];
    const float* We    = (const float*)d_in[4];
    const float* be    = (const float*)d_in[5];
    const float* W1    = (const float*)d_in[6];
    const float* b1    = (const float*)d_in[7];
    const float* W2    = (const float*)d_in[8];
    const float* b2    = (const float*)d_in[9];
    const float* gamma = (const float*)d_in[10];
    const float* beta  = (const float*)d_in[11];
    const float* Wp    = (const float*)d_in[12];
    const float* bp    = (const float*)d_in[13];
    const int* ei    = (const int*)d_in[14];
    const int* batch = (const int*)d_in[15];

    const int N = in_sizes[0] / 32;   // 50000
    const int E = in_sizes[1] / 16;   // 800000
    const int NB = (N + BNODES - 1) / BNODES;   // 782 buckets

    char* ws = (char*)d_ws;
    size_t off = 0;
    auto alloc = [&](size_t bytes) { char* p = ws + off; off += (bytes + 255) & ~(size_t)255; return p; };
    unsigned short* hb = (unsigned short*)alloc((size_t)(N + 1) * 128 * 2); // +1: zero row
    unsigned short* ag = (unsigned short*)alloc((size_t)N * 128 * 2);
    float* h2 = (float*)alloc((size_t)N * 128 * 4);
    // staging aliases h2 (dead before first fused_mlp write); 12.8MB < 25.6MB
    uint2* staging = (uint2*)h2;
    float* sums2   = (float*)alloc(32 * 256 * 4);
    float* coef    = (float*)alloc(256 * 4);
    float* pooled  = (float*)alloc(NGRAPHS * 128 * 4);
    float* mom     = (float*)alloc((size_t)N * 16 * 4);
    unsigned short* W0bf = (unsigned short*)alloc(128 * 32 * 2);
    unsigned short* W1bf = (unsigned short*)alloc(3 * 256 * 128 * 2);
    unsigned short* W2bf = (unsigned short*)alloc(3 * 128 * 256 * 2);
    int* rowptr   = (int*)alloc(((size_t)N + 1) * 4);
    int* subcnt   = (int*)alloc(((size_t)NB * 8 + 1) * 4);  // +1: ovfcnt tail
    int* ovfcnt   = subcnt + NB * 8;
    int* bucketbase = (int*)alloc(((size_t)NB + 1) * 4);
    uint4* ovfbuf = (uint4*)alloc((size_t)OVFCAP * 16);
    int* asrc     = (int*)alloc((size_t)E * 4);
    int* aeid     = (int*)alloc((size_t)E * 4);

    const dim3 blk(256);
    const int mblocks = (N + 63) / 64;
    const int mtiles = (N + 31) / 32;              // 32-node tiles
    const int fblocks = (mtiles + 2) / 3;          // exactly 3 tiles/block
    const int total4 = N * 32;
    const int eblocks = (E + 255) / 256;
    const float invN = 1.0f / (float)N;

    // --- CSR (bucketed build) + edge-attr moments (once, reused by layers) ---
    hipMemsetAsync(subcnt, 0, ((size_t)NB * 8 + 1) * 4, stream);
    edge_scatter<<<dim3(eblocks), blk, 0, stream>>>(
        ei, subcnt, staging, ovfcnt, ovfbuf, E);
    bucket_scan<<<dim3(1), blk, 0, stream>>>(subcnt, bucketbase, NB);
    csr_build<<<dim3(NB), blk, 0, stream>>>(
        subcnt, bucketbase, staging, ovfcnt, ovfbuf, asrc, aeid, rowptr, N, E);
    mom_gather<<<dim3(2048), blk, 0, stream>>>(aeid, rowptr, eattr, mom, N);

    // --- weight pre-conversion (+ hb zero-row init) ---
    conv_bf16_3<<<dim3(384), blk, 0, stream>>>(
        W0, W0bf, 128 * 32, W1, W1bf, 3 * 256 * 128, W2, W2bf, 3 * 128 * 256,
        hb + (size_t)N * 128);

    // h = bf16(x @ W0^T + b0)
    gemm_bt<32, false, false, true><<<dim3(mblocks, 2), blk, 0, stream>>>(
        x, W0bf, b0, (void*)hb, N, 128);

    // sums2 zeroed once here; bn_coef re-zeroes it after each read
    hipMemsetAsync(sums2, 0, 32 * 256 * 4, stream);

    for (int l = 0; l < LAYERS; ++l) {
        aggregate_kernel<<<dim3(2048), blk, 0, stream>>>(
            hb, asrc, rowptr, mom, We + l * 128 * 16, be + l * 128, ag, N);
        fused_mlp<<<dim3(fblocks), dim3(512), 0, stream>>>(
            ag, W1bf + l * 256 * 128, b1 + l * 256,
            W2bf + l * 128 * 256, b2 + l * 128, h2, sums2, N, mtiles);
        bn_coef<<<dim3(1), dim3(128), 0, stream>>>(
            sums2, gamma + l * 128, beta + l * 128, coef, invN);
        if (l < LAYERS - 1)
            bn_apply_bf16<<<dim3(1024), blk, 0, stream>>>(h2, coef, hb, total4);
    }

    // --- two-stage mean pool + folded final BN + head ---
    hipMemsetAsync(pooled, 0, NGRAPHS * 128 * 4, stream);
    pool_part<<<dim3(784), blk, 0, stream>>>(h2, batch, pooled, N);
    head_final<<<dim3(NGRAPHS), dim3(128), 0, stream>>>(
        pooled, batch, coef, Wp, bp, (float*)d_out, N);
}